// Round 1
// baseline (3104.770 us; speedup 1.0000x reference)
//
#include <hip/hip_runtime.h>
#include <hip/hip_bf16.h>
#include <math.h>
#include <stdint.h>

#define LDD 4096
#define LEE 8192
#define CDIM 512
#define CENC 256
#define HDIM 2048
#define NB 4
#define NHEAD 8
#define HD 64
#define NWIN 22
#define WINQ 256
#define WSTRIDE 192

__device__ __forceinline__ float gelu_f(float x) {
    return 0.5f * x * (1.0f + erff(x * 0.70710678118654752440f));
}

// ---------------------------------------------------------------------------
// Generic conv1x1 as batched GEMM: Out[b,o,l] = act( sum_c W[o,c]*X[b,c,l] + bias[o] )
// grid: (L/64, O/64, B), block: 256 threads. ACT: 0 = none, 1 = exact gelu.
// ---------------------------------------------------------------------------
template<int ACT>
__global__ __launch_bounds__(256)
void gemm_conv1x1(const float* __restrict__ W, const float* __restrict__ X,
                  const float* __restrict__ bias, float* __restrict__ Out,
                  int O, int C, int L)
{
    __shared__ float Ws[64][33];               // +1 pad: A-reads stride 33 -> distinct banks
    __shared__ __align__(16) float Xs[32][64];
    int tid = threadIdx.x;
    int tx = tid & 15, ty = tid >> 4;
    int l0 = blockIdx.x * 64;
    int o0 = blockIdx.y * 64;
    int b  = blockIdx.z;
    const float* Xb = X + (size_t)b * C * L;
    float acc[4][4] = {};

    for (int c0 = 0; c0 < C; c0 += 32) {
        // W tile 64x32 (rows contiguous in C)
        #pragma unroll
        for (int r = 0; r < 2; ++r) {
            int f4  = tid + 256 * r;           // 0..511
            int row = f4 >> 3;                 // 8 float4 per row
            int col = (f4 & 7) << 2;
            float4 w4 = *reinterpret_cast<const float4*>(&W[(size_t)(o0 + row) * C + c0 + col]);
            Ws[row][col + 0] = w4.x; Ws[row][col + 1] = w4.y;
            Ws[row][col + 2] = w4.z; Ws[row][col + 3] = w4.w;
        }
        // X tile 32x64 (rows contiguous in L)
        #pragma unroll
        for (int r = 0; r < 2; ++r) {
            int f4  = tid + 256 * r;
            int row = f4 >> 4;                 // 16 float4 per row
            int col = (f4 & 15) << 2;
            *reinterpret_cast<float4*>(&Xs[row][col]) =
                *reinterpret_cast<const float4*>(&Xb[(size_t)(c0 + row) * L + l0 + col]);
        }
        __syncthreads();
        #pragma unroll
        for (int kk = 0; kk < 32; ++kk) {
            float a[4];
            #pragma unroll
            for (int i = 0; i < 4; ++i) a[i] = Ws[ty * 4 + i][kk];
            float4 bx = *reinterpret_cast<const float4*>(&Xs[kk][tx << 2]);
            float bv[4] = {bx.x, bx.y, bx.z, bx.w};
            #pragma unroll
            for (int i = 0; i < 4; ++i)
                #pragma unroll
                for (int j = 0; j < 4; ++j)
                    acc[i][j] = fmaf(a[i], bv[j], acc[i][j]);
        }
        __syncthreads();
    }

    float* Ob = Out + (size_t)b * O * L;
    #pragma unroll
    for (int i = 0; i < 4; ++i) {
        int o = o0 + ty * 4 + i;
        float bb = bias[o];
        float4 r;
        r.x = acc[i][0] + bb; r.y = acc[i][1] + bb;
        r.z = acc[i][2] + bb; r.w = acc[i][3] + bb;
        if (ACT == 1) { r.x = gelu_f(r.x); r.y = gelu_f(r.y); r.z = gelu_f(r.z); r.w = gelu_f(r.w); }
        *reinterpret_cast<float4*>(&Ob[(size_t)o * L + l0 + (tx << 2)]) = r;
    }
}

// ---------------------------------------------------------------------------
// Instance norm over last axis; optional residual add. One block per (b,c) row.
// out[i] = (in[i]-mean)*rsqrt(var+1e-5) [+ res[i]]
// ---------------------------------------------------------------------------
__global__ __launch_bounds__(256)
void inorm_kernel(const float* __restrict__ in, const float* __restrict__ res,
                  float* __restrict__ out, int L)
{
    int row = blockIdx.x;
    const float* p = in + (size_t)row * L;
    float s = 0.f, ss = 0.f;
    for (int i = threadIdx.x * 4; i < L; i += 1024) {
        float4 v = *reinterpret_cast<const float4*>(&p[i]);
        s  += v.x + v.y + v.z + v.w;
        ss += v.x * v.x + v.y * v.y + v.z * v.z + v.w * v.w;
    }
    __shared__ float red[256], red2[256];
    red[threadIdx.x] = s; red2[threadIdx.x] = ss;
    __syncthreads();
    for (int step = 128; step > 0; step >>= 1) {
        if (threadIdx.x < step) {
            red[threadIdx.x]  += red[threadIdx.x + step];
            red2[threadIdx.x] += red2[threadIdx.x + step];
        }
        __syncthreads();
    }
    float m    = red[0] / (float)L;
    float var  = red2[0] / (float)L - m * m;
    float rstd = rsqrtf(var + 1e-5f);
    float* q = out + (size_t)row * L;
    const float* rr = res ? res + (size_t)row * L : nullptr;
    for (int i = threadIdx.x * 4; i < L; i += 1024) {
        float4 v = *reinterpret_cast<const float4*>(&p[i]);
        float4 o;
        o.x = (v.x - m) * rstd; o.y = (v.y - m) * rstd;
        o.z = (v.z - m) * rstd; o.w = (v.w - m) * rstd;
        if (rr) {
            float4 rv = *reinterpret_cast<const float4*>(&rr[i]);
            o.x += rv.x; o.y += rv.y; o.z += rv.z; o.w += rv.w;
        }
        *reinterpret_cast<float4*>(&q[i]) = o;
    }
}

// ---------------------------------------------------------------------------
// Transpose (B, NH*HD, L) -> (B, NH, L, HD). grid (L/64, NH, B)
// ---------------------------------------------------------------------------
__global__ __launch_bounds__(256)
void transpose_cl_to_ld(const float* __restrict__ in, float* __restrict__ out, int L)
{
    __shared__ float T[64][65];
    int l0 = blockIdx.x * 64;
    int hh = blockIdx.y, b = blockIdx.z;
    int tid = threadIdx.x;
    int ll = tid & 63;
    int dq = tid >> 6;
    #pragma unroll
    for (int i = 0; i < 16; ++i) {
        int d = dq + i * 4;
        T[d][ll] = in[((size_t)b * CDIM + hh * HD + d) * L + l0 + ll];
    }
    __syncthreads();
    int dd = tid & 63;
    int lq = tid >> 6;
    #pragma unroll
    for (int i = 0; i < 16; ++i) {
        int l = lq + i * 4;
        out[(((size_t)b * NHEAD + hh) * L + (l0 + l)) * HD + dd] = T[dd][l];
    }
}

// ---------------------------------------------------------------------------
// Windowed cross attention. One block per (window n, head, batch).
// qt: (B,NH,LD,HD) normalized q. k,v: (B,CDIM,LE) normalized.
// win out: (B,NH,NWIN,WINQ,HD)
// ---------------------------------------------------------------------------
__global__ __launch_bounds__(256)
void attn_win_kernel(const float* __restrict__ qt, const float* __restrict__ kbuf,
                     const float* __restrict__ vbuf, float* __restrict__ win)
{
    __shared__ uint32_t Ks[32][512];   // [d2][kk] packed bf16 pair (d=2*d2, 2*d2+1)  64KB
    __shared__ uint32_t Vs[512][32];   // [kk][d2 ^ (kk&31)] packed bf16 pair          64KB
    __shared__ float Ps[4][512];
    __shared__ float Qs[4][64];

    int n = blockIdx.x, hh = blockIdx.y, b = blockIdx.z;
    int s = n * WSTRIDE;
    int dec_end = min(s + WINQ, LDD);
    int nq = dec_end - s;                // 256 (or 64 for last window)
    int es = 2 * s;
    int ee = min(2 * dec_end, LEE);
    int ne = ee - es;                    // valid enc positions (<=512)

    int tid = threadIdx.x;
    int lane = tid & 63;
    int w = tid >> 6;

    // ---- stage K and V into LDS as bf16 pairs ----
    const size_t kvbase = ((size_t)b * CDIM + hh * HD) * LEE;
    for (int ii = 0; ii < 8; ++ii) {
        int d2 = (tid >> 6) + ii * 4;    // 0..31
        #pragma unroll
        for (int jj = 0; jj < 8; ++jj) {
            int kk = (tid & 63) + jj * 64;
            int ei = es + kk; if (ei > LEE - 1) ei = LEE - 1;
            size_t gi = kvbase + (size_t)(2 * d2) * LEE + ei;
            float klo = kbuf[gi], khi = kbuf[gi + LEE];
            float vlo = vbuf[gi], vhi = vbuf[gi + LEE];
            uint32_t kp = ((__float_as_uint(khi) + 0x8000u) & 0xffff0000u) |
                          ((__float_as_uint(klo) + 0x8000u) >> 16);
            uint32_t vp = ((__float_as_uint(vhi) + 0x8000u) & 0xffff0000u) |
                          ((__float_as_uint(vlo) + 0x8000u) >> 16);
            Ks[d2][kk] = kp;
            Vs[kk][d2 ^ (kk & 31)] = vp;
        }
    }
    __syncthreads();

    const size_t qbase = ((size_t)(b * NHEAD + hh) * LDD + s) * HD;
    const size_t wbase = ((size_t)(b * NHEAD + hh) * NWIN + n) * WINQ * HD;

    int ngroups = nq >> 2;
    for (int g = 0; g < ngroups; ++g) {
        int lr = g * 4 + w;                       // this wave's row (local)
        // stage this wave's q row (wave-local, no block sync needed)
        Qs[w][lane] = qt[qbase + (size_t)lr * HD + lane];

        // ---- QK^T: lane owns kk = j*64+lane ----
        float sc[8];
        #pragma unroll
        for (int j = 0; j < 8; ++j) sc[j] = 0.f;
        #pragma unroll 4
        for (int d2 = 0; d2 < 32; ++d2) {
            float qlo = Qs[w][2 * d2];
            float qhi = Qs[w][2 * d2 + 1];
            #pragma unroll
            for (int j = 0; j < 8; ++j) {
                uint32_t kp = Ks[d2][j * 64 + lane];
                sc[j] = fmaf(qlo, __uint_as_float(kp << 16), sc[j]);
                sc[j] = fmaf(qhi, __uint_as_float(kp & 0xffff0000u), sc[j]);
            }
        }
        // scale + mask + wave softmax
        float mx = -1e30f;
        #pragma unroll
        for (int j = 0; j < 8; ++j) {
            int kk = j * 64 + lane;
            sc[j] = (kk < ne) ? sc[j] * 0.125f : -1e30f;
            mx = fmaxf(mx, sc[j]);
        }
        #pragma unroll
        for (int off = 32; off > 0; off >>= 1) mx = fmaxf(mx, __shfl_xor(mx, off));
        float sum = 0.f;
        #pragma unroll
        for (int j = 0; j < 8; ++j) {
            float pv = __expf(sc[j] - mx);
            sum += pv;
            Ps[w][j * 64 + lane] = pv;
        }
        #pragma unroll
        for (int off = 32; off > 0; off >>= 1) sum += __shfl_xor(sum, off);
        float rsum = 1.f / sum;

        // ---- PV: lane owns d-pair d2p; halves split kk range ----
        int d2p = lane & 31;
        int half = lane >> 5;
        float a0 = 0.f, a1 = 0.f;
        #pragma unroll 8
        for (int t = 0; t < 256; ++t) {
            int kk = half * 256 + t;
            float pv = Ps[w][kk];
            uint32_t vp = Vs[kk][d2p ^ (kk & 31)];
            a0 = fmaf(pv, __uint_as_float(vp << 16), a0);
            a1 = fmaf(pv, __uint_as_float(vp & 0xffff0000u), a1);
        }
        a0 += __shfl_xor(a0, 32);
        a1 += __shfl_xor(a1, 32);
        if (lane < 32) {
            float2 o = make_float2(a0 * rsum, a1 * rsum);
            *reinterpret_cast<float2*>(&win[wbase + (size_t)lr * HD + 2 * d2p]) = o;
        }
    }
}

// ---------------------------------------------------------------------------
// Overlap-add gather + count-normalize + transpose to (B, CDIM, LD).
// grid (LD/64, NH, B)
// ---------------------------------------------------------------------------
__global__ __launch_bounds__(256)
void attn_finalize(const float* __restrict__ win, float* __restrict__ out)
{
    __shared__ float T[64][65];
    int l0 = blockIdx.x * 64;
    int hh = blockIdx.y, b = blockIdx.z;
    int tid = threadIdx.x;
    int d = tid & 63;
    int lq = tid >> 6;
    #pragma unroll
    for (int i = 0; i < 16; ++i) {
        int ll = lq + i * 4;
        int l = l0 + ll;
        int n1 = min(NWIN - 1, l / WSTRIDE);
        int n0 = (l >= 64) ? ((l - 64) / WSTRIDE) : 0;   // ceil((l-255)/192) clamped
        float acc = 0.f;
        for (int n = n0; n <= n1; ++n) {
            int qrow = l - n * WSTRIDE;                  // in [0,255], always valid
            acc += win[(((size_t)(b * NHEAD + hh) * NWIN + n) * WINQ + qrow) * HD + d];
        }
        T[ll][d] = acc / (float)(n1 - n0 + 1);
    }
    __syncthreads();
    int ll2 = tid & 63;
    int dd = tid >> 6;
    #pragma unroll
    for (int i = 0; i < 16; ++i) {
        int d2 = dd + i * 4;
        out[((size_t)b * CDIM + hh * HD + d2) * LDD + l0 + ll2] = T[ll2][d2];
    }
}

// ---------------------------------------------------------------------------
extern "C" void kernel_launch(void* const* d_in, const int* in_sizes, int n_in,
                              void* d_out, int out_size, void* d_ws, size_t ws_size,
                              hipStream_t stream)
{
    const float* x_dec = (const float*)d_in[0];
    const float* x_enc = (const float*)d_in[1];
    const float* wq = (const float*)d_in[2];
    const float* bq = (const float*)d_in[3];
    const float* wk = (const float*)d_in[4];
    const float* bk = (const float*)d_in[5];
    const float* wv = (const float*)d_in[6];
    const float* bv = (const float*)d_in[7];
    const float* wo = (const float*)d_in[8];
    const float* bo = (const float*)d_in[9];
    const float* w1 = (const float*)d_in[10];
    const float* b1 = (const float*)d_in[11];
    const float* w2 = (const float*)d_in[12];
    const float* b2 = (const float*)d_in[13];
    float* out = (float*)d_out;

    // workspace layout (floats), peak 61,865,984 floats = 247.5 MB
    float* ws = (float*)d_ws;
    const size_t SZ_Q = (size_t)NB * CDIM * LDD;   // 8388608
    const size_t SZ_K = (size_t)NB * CDIM * LEE;   // 16777216
    const size_t SZ_W = (size_t)NB * NHEAD * NWIN * WINQ * HD; // 11534336
    float* q    = ws;                  // q raw/normalized -> later attn_out
    float* kbuf = q + SZ_Q;            // k -> later h (spans k+v)
    float* vbuf = kbuf + SZ_K;         // v
    float* qt   = vbuf + SZ_K;         // q transposed -> later xo
    float* winb = qt + SZ_Q;           // attention window outputs -> later x
    float* attn_out = q;
    float* xo   = qt;
    float* xres = winb;
    float* hbuf = kbuf;                // 2*SZ_K = 33554432 = NB*HDIM*LDD exactly

    dim3 blk(256);

    // 1. q = IN(conv(x_dec, wq, bq)); transpose to (b,h,l,d)
    gemm_conv1x1<0><<<dim3(LDD / 64, CDIM / 64, NB), blk, 0, stream>>>(wq, x_dec, bq, q, CDIM, CDIM, LDD);
    inorm_kernel<<<dim3(NB * CDIM), blk, 0, stream>>>(q, nullptr, q, LDD);
    transpose_cl_to_ld<<<dim3(LDD / 64, NHEAD, NB), blk, 0, stream>>>(q, qt, LDD);

    // 2. k, v
    gemm_conv1x1<0><<<dim3(LEE / 64, CDIM / 64, NB), blk, 0, stream>>>(wk, x_enc, bk, kbuf, CDIM, CENC, LEE);
    inorm_kernel<<<dim3(NB * CDIM), blk, 0, stream>>>(kbuf, nullptr, kbuf, LEE);
    gemm_conv1x1<0><<<dim3(LEE / 64, CDIM / 64, NB), blk, 0, stream>>>(wv, x_enc, bv, vbuf, CDIM, CENC, LEE);
    inorm_kernel<<<dim3(NB * CDIM), blk, 0, stream>>>(vbuf, nullptr, vbuf, LEE);

    // 3. windowed attention + overlap-add finalize
    attn_win_kernel<<<dim3(NWIN, NHEAD, NB), blk, 0, stream>>>(qt, kbuf, vbuf, winb);
    attn_finalize<<<dim3(LDD / 64, NHEAD, NB), blk, 0, stream>>>(winb, attn_out);

    // 4. x = IN(conv(attn_out, wo, bo)) + residual
    gemm_conv1x1<0><<<dim3(LDD / 64, CDIM / 64, NB), blk, 0, stream>>>(wo, attn_out, bo, xo, CDIM, CDIM, LDD);
    inorm_kernel<<<dim3(NB * CDIM), blk, 0, stream>>>(xo, x_dec, xres, LDD);

    // 5. FFN: h = gelu(conv(x, w1, b1)); y = IN(conv(h, w2, b2)) + x
    gemm_conv1x1<1><<<dim3(LDD / 64, HDIM / 64, NB), blk, 0, stream>>>(w1, xres, b1, hbuf, HDIM, CDIM, LDD);
    gemm_conv1x1<0><<<dim3(LDD / 64, CDIM / 64, NB), blk, 0, stream>>>(w2, hbuf, b2, out, CDIM, HDIM, LDD);
    inorm_kernel<<<dim3(NB * CDIM), blk, 0, stream>>>(out, xres, out, LDD);

    (void)in_sizes; (void)n_in; (void)out_size; (void)ws_size;
}

// Round 2
// 1616.997 us; speedup vs baseline: 1.9201x; 1.9201x over previous
//
#include <hip/hip_runtime.h>
#include <hip/hip_bf16.h>
#include <math.h>
#include <stdint.h>

#define LDD 4096
#define LEE 8192
#define CDIM 512
#define CENC 256
#define HDIM 2048
#define NB 4
#define NHEAD 8
#define HD 64
#define NWIN 22
#define WINQ 256
#define WSTRIDE 192

typedef __attribute__((ext_vector_type(8))) short bf16x8;
typedef __attribute__((ext_vector_type(4))) float f32x4;
typedef __attribute__((ext_vector_type(2))) unsigned int u32x2;

__device__ __forceinline__ float gelu_f(float x) {
    return 0.5f * x * (1.0f + erff(x * 0.70710678118654752440f));
}

__device__ __forceinline__ uint32_t pack2(float lo, float hi) {
    return ((__float_as_uint(hi) + 0x8000u) & 0xffff0000u) |
           ((__float_as_uint(lo) + 0x8000u) >> 16);
}
__device__ __forceinline__ short bfc(float x) {
    return (short)((__float_as_uint(x) + 0x8000u) >> 16);
}

// ---------------------------------------------------------------------------
// Generic conv1x1 as batched GEMM: Out[b,o,l] = act( sum_c W[o,c]*X[b,c,l] + bias[o] )
// ---------------------------------------------------------------------------
template<int ACT>
__global__ __launch_bounds__(256)
void gemm_conv1x1(const float* __restrict__ W, const float* __restrict__ X,
                  const float* __restrict__ bias, float* __restrict__ Out,
                  int O, int C, int L)
{
    __shared__ float Ws[64][33];
    __shared__ __align__(16) float Xs[32][64];
    int tid = threadIdx.x;
    int tx = tid & 15, ty = tid >> 4;
    int l0 = blockIdx.x * 64;
    int o0 = blockIdx.y * 64;
    int b  = blockIdx.z;
    const float* Xb = X + (size_t)b * C * L;
    float acc[4][4] = {};

    for (int c0 = 0; c0 < C; c0 += 32) {
        #pragma unroll
        for (int r = 0; r < 2; ++r) {
            int f4  = tid + 256 * r;
            int row = f4 >> 3;
            int col = (f4 & 7) << 2;
            float4 w4 = *reinterpret_cast<const float4*>(&W[(size_t)(o0 + row) * C + c0 + col]);
            Ws[row][col + 0] = w4.x; Ws[row][col + 1] = w4.y;
            Ws[row][col + 2] = w4.z; Ws[row][col + 3] = w4.w;
        }
        #pragma unroll
        for (int r = 0; r < 2; ++r) {
            int f4  = tid + 256 * r;
            int row = f4 >> 4;
            int col = (f4 & 15) << 2;
            *reinterpret_cast<float4*>(&Xs[row][col]) =
                *reinterpret_cast<const float4*>(&Xb[(size_t)(c0 + row) * L + l0 + col]);
        }
        __syncthreads();
        #pragma unroll
        for (int kk = 0; kk < 32; ++kk) {
            float a[4];
            #pragma unroll
            for (int i = 0; i < 4; ++i) a[i] = Ws[ty * 4 + i][kk];
            float4 bx = *reinterpret_cast<const float4*>(&Xs[kk][tx << 2]);
            float bv[4] = {bx.x, bx.y, bx.z, bx.w};
            #pragma unroll
            for (int i = 0; i < 4; ++i)
                #pragma unroll
                for (int j = 0; j < 4; ++j)
                    acc[i][j] = fmaf(a[i], bv[j], acc[i][j]);
        }
        __syncthreads();
    }

    float* Ob = Out + (size_t)b * O * L;
    #pragma unroll
    for (int i = 0; i < 4; ++i) {
        int o = o0 + ty * 4 + i;
        float bb = bias[o];
        float4 r;
        r.x = acc[i][0] + bb; r.y = acc[i][1] + bb;
        r.z = acc[i][2] + bb; r.w = acc[i][3] + bb;
        if (ACT == 1) { r.x = gelu_f(r.x); r.y = gelu_f(r.y); r.z = gelu_f(r.z); r.w = gelu_f(r.w); }
        *reinterpret_cast<float4*>(&Ob[(size_t)o * L + l0 + (tx << 2)]) = r;
    }
}

// ---------------------------------------------------------------------------
// Instance norm over last axis; optional residual add. One block per (b,c) row.
// ---------------------------------------------------------------------------
__global__ __launch_bounds__(256)
void inorm_kernel(const float* __restrict__ in, const float* __restrict__ res,
                  float* __restrict__ out, int L)
{
    int row = blockIdx.x;
    const float* p = in + (size_t)row * L;
    float s = 0.f, ss = 0.f;
    for (int i = threadIdx.x * 4; i < L; i += 1024) {
        float4 v = *reinterpret_cast<const float4*>(&p[i]);
        s  += v.x + v.y + v.z + v.w;
        ss += v.x * v.x + v.y * v.y + v.z * v.z + v.w * v.w;
    }
    __shared__ float red[256], red2[256];
    red[threadIdx.x] = s; red2[threadIdx.x] = ss;
    __syncthreads();
    for (int step = 128; step > 0; step >>= 1) {
        if (threadIdx.x < step) {
            red[threadIdx.x]  += red[threadIdx.x + step];
            red2[threadIdx.x] += red2[threadIdx.x + step];
        }
        __syncthreads();
    }
    float m    = red[0] / (float)L;
    float var  = red2[0] / (float)L - m * m;
    float rstd = rsqrtf(var + 1e-5f);
    float* q = out + (size_t)row * L;
    const float* rr = res ? res + (size_t)row * L : nullptr;
    for (int i = threadIdx.x * 4; i < L; i += 1024) {
        float4 v = *reinterpret_cast<const float4*>(&p[i]);
        float4 o;
        o.x = (v.x - m) * rstd; o.y = (v.y - m) * rstd;
        o.z = (v.z - m) * rstd; o.w = (v.w - m) * rstd;
        if (rr) {
            float4 rv = *reinterpret_cast<const float4*>(&rr[i]);
            o.x += rv.x; o.y += rv.y; o.z += rv.z; o.w += rv.w;
        }
        *reinterpret_cast<float4*>(&q[i]) = o;
    }
}

// ---------------------------------------------------------------------------
// Transpose (B, NH*HD, L) -> (B, NH, L, HD). grid (L/64, NH, B)
// ---------------------------------------------------------------------------
__global__ __launch_bounds__(256)
void transpose_cl_to_ld(const float* __restrict__ in, float* __restrict__ out, int L)
{
    __shared__ float T[64][65];
    int l0 = blockIdx.x * 64;
    int hh = blockIdx.y, b = blockIdx.z;
    int tid = threadIdx.x;
    int ll = tid & 63;
    int dq = tid >> 6;
    #pragma unroll
    for (int i = 0; i < 16; ++i) {
        int d = dq + i * 4;
        T[d][ll] = in[((size_t)b * CDIM + hh * HD + d) * L + l0 + ll];
    }
    __syncthreads();
    int dd = tid & 63;
    int lq = tid >> 6;
    #pragma unroll
    for (int i = 0; i < 16; ++i) {
        int l = lq + i * 4;
        out[(((size_t)b * NHEAD + hh) * L + (l0 + l)) * HD + dd] = T[dd][l];
    }
}

// ---------------------------------------------------------------------------
// MFMA windowed cross attention. One block (512 thr / 8 waves) per (n, h, b).
// qt: (B,NH,LD,HD) f32 normalized q. kbuf/vbuf: (B,CDIM,LE) f32 normalized.
// win out: (B,NH,NWIN,WINQ,HD) f32.
//
// Per 16x16 tile computes S^T = K·Q (swapped operands) so each lane owns one
// q-row (col = lane&15) -> softmax reduce = 2 shfl_xor. O^T = V^T·P^T.
// K LDS [kpos][d] bf16, V LDS [d][kpos] bf16, both XOR-swizzled (G4).
// ---------------------------------------------------------------------------
__global__ __launch_bounds__(512)
void attn_win_mfma(const float* __restrict__ qt, const float* __restrict__ kbuf,
                   const float* __restrict__ vbuf, float* __restrict__ win)
{
    __shared__ char KB[65536];                // K: [512][64] bf16, byte ^= ((kpos&7)<<4)
    __shared__ char VB[65536];                // V: [64][512] bf16, byte ^= ((d&7)<<4)
    __shared__ uint32_t PL[8][16][20];        // per-wave P bounce, pad 20 (2-way)

    int n = blockIdx.x, hh = blockIdx.y, b = blockIdx.z;
    int s = n * WSTRIDE;
    int nq = min(s + WINQ, LDD) - s;          // 256 (64 for last window)
    int es = 2 * s;
    int ne = min(2 * (s + nq), LEE) - es;     // 512 (128 for last window)

    int tid = threadIdx.x;
    int lane = tid & 63;
    int w = tid >> 6;
    int q16 = lane & 15;                      // q-row within tile (C/D col)
    int g = lane >> 4;                        // lane group 0..3

    // ---- stage K: transpose (d-major global) -> [kpos][d] bf16 swizzled ----
    const size_t kvoff = ((size_t)b * CDIM + hh * HD) * LEE + es;
    {
        const float* ksrc = kbuf + kvoff;
        int d2s = tid >> 4;                   // 0..31 (d-pair)
        int kb0 = (tid & 15) * 4;
        #pragma unroll
        for (int i = 0; i < 8; ++i) {
            int kpos0 = kb0 + i * 64;
            int kc = min(kpos0, ne - 4);      // clamp reads in-bounds; masked later
            float4 lo = *reinterpret_cast<const float4*>(&ksrc[(size_t)(2 * d2s) * LEE + kc]);
            float4 hi = *reinterpret_cast<const float4*>(&ksrc[(size_t)(2 * d2s + 1) * LEE + kc]);
            float lof[4] = {lo.x, lo.y, lo.z, lo.w};
            float hif[4] = {hi.x, hi.y, hi.z, hi.w};
            #pragma unroll
            for (int j = 0; j < 4; ++j) {
                int kp = kpos0 + j;
                int byte = kp * 128 + ((d2s * 4) ^ ((kp & 7) << 4));
                *reinterpret_cast<uint32_t*>(&KB[byte]) = pack2(lof[j], hif[j]);
            }
        }
    }
    // ---- stage V: direct layout [d][kpos] bf16 swizzled ----
    {
        const float* vsrc = vbuf + kvoff;
        #pragma unroll
        for (int i = 0; i < 16; ++i) {
            int f4 = tid + i * 512;           // 8192 float4s total
            int d = f4 >> 7;
            int kpos0 = (f4 & 127) * 4;
            int kc = min(kpos0, ne - 4);
            float4 v = *reinterpret_cast<const float4*>(&vsrc[(size_t)d * LEE + kc]);
            int byte = d * 1024 + ((kpos0 * 2) ^ ((d & 7) << 4));
            u32x2 pr; pr[0] = pack2(v.x, v.y); pr[1] = pack2(v.z, v.w);
            *reinterpret_cast<u32x2*>(&VB[byte]) = pr;
        }
    }
    __syncthreads();

    const float* qtb = qt + ((size_t)(b * NHEAD + hh) * LDD + s) * HD;
    const size_t wbase = ((size_t)(b * NHEAD + hh) * NWIN + n) * (WINQ * HD);

    #pragma unroll 1
    for (int t = 0; t < 2; ++t) {
        int qrow_loc = w * 32 + t * 16 + q16;
        int qr = min(qrow_loc, nq - 1);

        // Q B-frags: col = q-row = lane&15, k-elem d = kd*32 + g*8 + j
        bf16x8 bq[2];
        #pragma unroll
        for (int kd = 0; kd < 2; ++kd) {
            const float* qp = qtb + (size_t)qr * HD + kd * 32 + g * 8;
            float4 a0 = *reinterpret_cast<const float4*>(qp);
            float4 a1 = *reinterpret_cast<const float4*>(qp + 4);
            bf16x8 f;
            f[0] = bfc(a0.x); f[1] = bfc(a0.y); f[2] = bfc(a0.z); f[3] = bfc(a0.w);
            f[4] = bfc(a1.x); f[5] = bfc(a1.y); f[6] = bfc(a1.z); f[7] = bfc(a1.w);
            bq[kd] = f;
        }

        f32x4 ot[4];
        #pragma unroll
        for (int dt = 0; dt < 4; ++dt) { ot[dt][0]=0.f; ot[dt][1]=0.f; ot[dt][2]=0.f; ot[dt][3]=0.f; }
        float m = -3e38f, ssum = 0.f;

        for (int cc = 0; cc < 8; ++cc) {
            // ---- S^T tiles: A = K (16 kpos x 32 d), B = Q ----
            f32x4 st[4];
            #pragma unroll
            for (int ct = 0; ct < 4; ++ct) {
                int kpos = cc * 64 + ct * 16 + q16;
                int rb = kpos * 128;
                int sw = (kpos & 7) << 4;
                bf16x8 ka0 = *reinterpret_cast<const bf16x8*>(&KB[rb + ((g * 16) ^ sw)]);
                bf16x8 ka1 = *reinterpret_cast<const bf16x8*>(&KB[rb + ((64 + g * 16) ^ sw)]);
                f32x4 z; z[0]=0.f; z[1]=0.f; z[2]=0.f; z[3]=0.f;
                z = __builtin_amdgcn_mfma_f32_16x16x32_bf16(ka0, bq[0], z, 0, 0, 0);
                z = __builtin_amdgcn_mfma_f32_16x16x32_bf16(ka1, bq[1], z, 0, 0, 0);
                st[ct] = z;
            }
            // ---- scale + mask + online max ----
            float pmax = -3e38f;
            #pragma unroll
            for (int ct = 0; ct < 4; ++ct) {
                #pragma unroll
                for (int r = 0; r < 4; ++r) {
                    int kg = cc * 64 + ct * 16 + g * 4 + r;
                    float x = (kg < ne) ? st[ct][r] * 0.125f : -1e30f;
                    st[ct][r] = x;
                    pmax = fmaxf(pmax, x);
                }
            }
            pmax = fmaxf(pmax, __shfl_xor(pmax, 16));
            pmax = fmaxf(pmax, __shfl_xor(pmax, 32));
            float mnew = fmaxf(m, pmax);
            float corr = __expf(m - mnew);
            m = mnew;
            ssum *= corr;
            #pragma unroll
            for (int dt = 0; dt < 4; ++dt) {
                ot[dt][0] *= corr; ot[dt][1] *= corr;
                ot[dt][2] *= corr; ot[dt][3] *= corr;
            }
            // ---- P = exp, pack bf16, bounce via LDS to B-frag layout, PV ----
            #pragma unroll
            for (int o32 = 0; o32 < 2; ++o32) {
                #pragma unroll
                for (int ti = 0; ti < 2; ++ti) {
                    int ct = o32 * 2 + ti;
                    float p0 = __expf(st[ct][0] - m);
                    float p1 = __expf(st[ct][1] - m);
                    float p2 = __expf(st[ct][2] - m);
                    float p3 = __expf(st[ct][3] - m);
                    ssum += p0 + p1 + p2 + p3;
                    u32x2 pr; pr[0] = pack2(p0, p1); pr[1] = pack2(p2, p3);
                    *reinterpret_cast<u32x2*>(&PL[w][q16][ti * 8 + g * 2]) = pr;
                }
                bf16x8 pb = *reinterpret_cast<const bf16x8*>(&PL[w][q16][g * 4]);
                #pragma unroll
                for (int dt = 0; dt < 4; ++dt) {
                    int d = dt * 16 + q16;
                    int byte = d * 1024 + ((cc * 128 + o32 * 64 + g * 16) ^ ((d & 7) << 4));
                    bf16x8 va = *reinterpret_cast<const bf16x8*>(&VB[byte]);
                    ot[dt] = __builtin_amdgcn_mfma_f32_16x16x32_bf16(va, pb, ot[dt], 0, 0, 0);
                }
            }
        }
        // ---- epilogue ----
        float stot = ssum + __shfl_xor(ssum, 16);
        stot += __shfl_xor(stot, 32);
        float rs = 1.f / stot;
        if (qrow_loc < nq) {
            float* wp = &win[wbase + (size_t)qrow_loc * HD];
            #pragma unroll
            for (int dt = 0; dt < 4; ++dt) {
                float4 o = make_float4(ot[dt][0] * rs, ot[dt][1] * rs,
                                       ot[dt][2] * rs, ot[dt][3] * rs);
                *reinterpret_cast<float4*>(&wp[dt * 16 + g * 4]) = o;
            }
        }
    }
}

// ---------------------------------------------------------------------------
// Overlap-add gather + count-normalize + transpose to (B, CDIM, LD).
// ---------------------------------------------------------------------------
__global__ __launch_bounds__(256)
void attn_finalize(const float* __restrict__ win, float* __restrict__ out)
{
    __shared__ float T[64][65];
    int l0 = blockIdx.x * 64;
    int hh = blockIdx.y, b = blockIdx.z;
    int tid = threadIdx.x;
    int d = tid & 63;
    int lq = tid >> 6;
    #pragma unroll
    for (int i = 0; i < 16; ++i) {
        int ll = lq + i * 4;
        int l = l0 + ll;
        int n1 = min(NWIN - 1, l / WSTRIDE);
        int n0 = (l >= 64) ? ((l - 64) / WSTRIDE) : 0;
        float acc = 0.f;
        for (int n = n0; n <= n1; ++n) {
            int qrow = l - n * WSTRIDE;
            acc += win[(((size_t)(b * NHEAD + hh) * NWIN + n) * WINQ + qrow) * HD + d];
        }
        T[ll][d] = acc / (float)(n1 - n0 + 1);
    }
    __syncthreads();
    int ll2 = tid & 63;
    int dd = tid >> 6;
    #pragma unroll
    for (int i = 0; i < 16; ++i) {
        int d2 = dd + i * 4;
        out[((size_t)b * CDIM + hh * HD + d2) * LDD + l0 + ll2] = T[ll2][d2];
    }
}

// ---------------------------------------------------------------------------
extern "C" void kernel_launch(void* const* d_in, const int* in_sizes, int n_in,
                              void* d_out, int out_size, void* d_ws, size_t ws_size,
                              hipStream_t stream)
{
    const float* x_dec = (const float*)d_in[0];
    const float* x_enc = (const float*)d_in[1];
    const float* wq = (const float*)d_in[2];
    const float* bq = (const float*)d_in[3];
    const float* wk = (const float*)d_in[4];
    const float* bk = (const float*)d_in[5];
    const float* wv = (const float*)d_in[6];
    const float* bv = (const float*)d_in[7];
    const float* wo = (const float*)d_in[8];
    const float* bo = (const float*)d_in[9];
    const float* w1 = (const float*)d_in[10];
    const float* b1 = (const float*)d_in[11];
    const float* w2 = (const float*)d_in[12];
    const float* b2 = (const float*)d_in[13];
    float* out = (float*)d_out;

    float* ws = (float*)d_ws;
    const size_t SZ_Q = (size_t)NB * CDIM * LDD;
    const size_t SZ_K = (size_t)NB * CDIM * LEE;
    float* q    = ws;
    float* kbuf = q + SZ_Q;
    float* vbuf = kbuf + SZ_K;
    float* qtb  = vbuf + SZ_K;
    float* winb = qtb + SZ_Q;
    float* attn_out = q;
    float* xo   = qtb;
    float* xres = winb;
    float* hbuf = kbuf;

    dim3 blk(256);

    gemm_conv1x1<0><<<dim3(LDD / 64, CDIM / 64, NB), blk, 0, stream>>>(wq, x_dec, bq, q, CDIM, CDIM, LDD);
    inorm_kernel<<<dim3(NB * CDIM), blk, 0, stream>>>(q, nullptr, q, LDD);
    transpose_cl_to_ld<<<dim3(LDD / 64, NHEAD, NB), blk, 0, stream>>>(q, qtb, LDD);

    gemm_conv1x1<0><<<dim3(LEE / 64, CDIM / 64, NB), blk, 0, stream>>>(wk, x_enc, bk, kbuf, CDIM, CENC, LEE);
    inorm_kernel<<<dim3(NB * CDIM), blk, 0, stream>>>(kbuf, nullptr, kbuf, LEE);
    gemm_conv1x1<0><<<dim3(LEE / 64, CDIM / 64, NB), blk, 0, stream>>>(wv, x_enc, bv, vbuf, CDIM, CENC, LEE);
    inorm_kernel<<<dim3(NB * CDIM), blk, 0, stream>>>(vbuf, nullptr, vbuf, LEE);

    attn_win_mfma<<<dim3(NWIN, NHEAD, NB), dim3(512), 0, stream>>>(qtb, kbuf, vbuf, winb);
    attn_finalize<<<dim3(LDD / 64, NHEAD, NB), blk, 0, stream>>>(winb, attn_out);

    gemm_conv1x1<0><<<dim3(LDD / 64, CDIM / 64, NB), blk, 0, stream>>>(wo, attn_out, bo, xo, CDIM, CDIM, LDD);
    inorm_kernel<<<dim3(NB * CDIM), blk, 0, stream>>>(xo, x_dec, xres, LDD);

    gemm_conv1x1<1><<<dim3(LDD / 64, HDIM / 64, NB), blk, 0, stream>>>(w1, xres, b1, hbuf, HDIM, CDIM, LDD);
    gemm_conv1x1<0><<<dim3(LDD / 64, CDIM / 64, NB), blk, 0, stream>>>(w2, hbuf, b2, out, CDIM, HDIM, LDD);
    inorm_kernel<<<dim3(NB * CDIM), blk, 0, stream>>>(out, xres, out, LDD);

    (void)in_sizes; (void)n_in; (void)out_size; (void)ws_size;
}

// Round 3
// 575.512 us; speedup vs baseline: 5.3948x; 2.8097x over previous
//
#include <hip/hip_runtime.h>
#include <hip/hip_bf16.h>
#include <math.h>
#include <stdint.h>

#define LDD 4096
#define LEE 8192
#define CDIM 512
#define CENC 256
#define HDIM 2048
#define NB 4
#define NHEAD 8
#define HD 64
#define NWIN 22
#define WINQ 256
#define WSTRIDE 192

typedef __attribute__((ext_vector_type(8))) short bf16x8;
typedef __attribute__((ext_vector_type(8))) unsigned short u16x8;
typedef __attribute__((ext_vector_type(4))) float f32x4;
typedef __attribute__((ext_vector_type(2))) unsigned int u32x2;
typedef unsigned short ushort_t;

__device__ __forceinline__ float gelu_f(float x) {
    return 0.5f * x * (1.0f + erff(x * 0.70710678118654752440f));
}
__device__ __forceinline__ uint32_t pack2(float lo, float hi) {
    return ((__float_as_uint(hi) + 0x8000u) & 0xffff0000u) |
           ((__float_as_uint(lo) + 0x8000u) >> 16);
}
__device__ __forceinline__ ushort_t bfc(float x) {
    return (ushort_t)((__float_as_uint(x) + 0x8000u) >> 16);
}
__device__ __forceinline__ float bf2f(ushort_t u) {
    return __uint_as_float(((uint32_t)u) << 16);
}
__device__ __forceinline__ void gload16(const void* g, void* l) {
    __builtin_amdgcn_global_load_lds(
        (const __attribute__((address_space(1))) void*)g,
        (__attribute__((address_space(3))) void*)l, 16, 0, 0);
}

// ---------------------------------------------------------------------------
// f32 -> bf16 convert (weights). n divisible by 4.
// ---------------------------------------------------------------------------
__global__ __launch_bounds__(256)
void cvt_bf16(const float* __restrict__ in, ushort_t* __restrict__ out, int n)
{
    int i = (blockIdx.x * 256 + threadIdx.x) * 4;
    if (i < n) {
        float4 v = *reinterpret_cast<const float4*>(&in[i]);
        u32x2 p; p[0] = pack2(v.x, v.y); p[1] = pack2(v.z, v.w);
        *reinterpret_cast<u32x2*>(&out[i]) = p;
    }
}

// ---------------------------------------------------------------------------
// Transpose+convert: in f32 [B][C][L] -> outb bf16 [B][L][C] (+ outf f32).
// grid (L/64, C/64, B)
// ---------------------------------------------------------------------------
template<int F32OUT>
__global__ __launch_bounds__(256)
void tcvt(const float* __restrict__ in, ushort_t* __restrict__ outb,
          float* __restrict__ outf, int C, int L)
{
    __shared__ float T[64][65];
    int l0 = blockIdx.x * 64, c0 = blockIdx.y * 64, b = blockIdx.z;
    int tid = threadIdx.x;
    int ll = tid & 63, cq = tid >> 6;
    #pragma unroll
    for (int i = 0; i < 16; ++i) {
        int c = cq + i * 4;
        T[c][ll] = in[((size_t)b * C + c0 + c) * L + l0 + ll];
    }
    __syncthreads();
    int cc = tid & 63, lq = tid >> 6;
    #pragma unroll
    for (int i = 0; i < 16; ++i) {
        int l = lq + i * 4;
        float v = T[cc][l];
        size_t idx = ((size_t)b * L + l0 + l) * C + c0 + cc;
        outb[idx] = bfc(v);
        if (F32OUT) outf[idx] = v;
    }
}

// ---------------------------------------------------------------------------
// MFMA GEMM: OutT[b][m][n] = sum_k A[b][m][k] * W[n][k] + bias[n]
// A bf16 [B][M][K], W bf16 [N][K]. 128x128 tile, BK=32, 256 thr (4 waves).
// grid (N/128, M/128, B). EPI 0: f32 out. EPI 1: bf16 out + gelu.
// ---------------------------------------------------------------------------
template<int EPI>
__global__ __launch_bounds__(256)
void mgemm(const ushort_t* __restrict__ A, const ushort_t* __restrict__ W,
           const float* __restrict__ bias, void* __restrict__ Out,
           int M, int N, int K)
{
    __shared__ __align__(16) ushort_t As[4096];  // 128 rows x 32 k, swizzled
    __shared__ __align__(16) ushort_t Bs[4096];

    int Nt = gridDim.x;
    int flat = blockIdx.y * Nt + blockIdx.x;
    int nwg = Nt * gridDim.y;
    int sw = (flat & 7) * (nwg >> 3) + (flat >> 3);   // nwg % 8 == 0 always here
    int nb = sw % Nt, mb = sw / Nt;
    int b = blockIdx.z;
    int m0 = mb * 128, n0 = nb * 128;

    int tid = threadIdx.x;
    int lane = tid & 63;
    int w = tid >> 6;
    int q16 = lane & 15, g = lane >> 4;
    int wr = w >> 1, wc = w & 1;

    // staging source precompute (pre-swizzled per-lane global chunk)
    const ushort_t* Ag[2]; const ushort_t* Wg[2];
    ushort_t* AsL[2]; ushort_t* BsL[2];
    #pragma unroll
    for (int i = 0; i < 2; ++i) {
        int o = w * 2048 + i * 1024 + lane * 16;     // LDS byte offset
        int row = o >> 6;
        int slot = (o >> 4) & 3;
        int c4 = slot ^ ((row >> 1) & 3);
        Ag[i] = A + ((size_t)b * M + m0 + row) * K + c4 * 8;
        Wg[i] = W + ((size_t)(n0 + row)) * K + c4 * 8;
        AsL[i] = &As[w * 1024 + i * 512];
        BsL[i] = &Bs[w * 1024 + i * 512];
    }

    f32x4 acc[4][4];
    #pragma unroll
    for (int mt = 0; mt < 4; ++mt)
        #pragma unroll
        for (int nt = 0; nt < 4; ++nt)
            #pragma unroll
            for (int e = 0; e < 4; ++e) acc[mt][nt][e] = 0.f;

    for (int k0 = 0; k0 < K; k0 += 32) {
        __syncthreads();
        gload16(Ag[0] + k0, AsL[0]);
        gload16(Ag[1] + k0, AsL[1]);
        gload16(Wg[0] + k0, BsL[0]);
        gload16(Wg[1] + k0, BsL[1]);
        __syncthreads();

        bf16x8 ka[4], kb[4];
        #pragma unroll
        for (int mt = 0; mt < 4; ++mt) {
            int r = wr * 64 + mt * 16 + q16;
            int byte = r * 64 + ((g * 16) ^ ((r & 6) << 3));
            ka[mt] = *reinterpret_cast<const bf16x8*>(reinterpret_cast<const char*>(As) + byte);
        }
        #pragma unroll
        for (int nt = 0; nt < 4; ++nt) {
            int r = wc * 64 + nt * 16 + q16;
            int byte = r * 64 + ((g * 16) ^ ((r & 6) << 3));
            kb[nt] = *reinterpret_cast<const bf16x8*>(reinterpret_cast<const char*>(Bs) + byte);
        }
        #pragma unroll
        for (int mt = 0; mt < 4; ++mt)
            #pragma unroll
            for (int nt = 0; nt < 4; ++nt)
                acc[mt][nt] = __builtin_amdgcn_mfma_f32_16x16x32_bf16(ka[mt], kb[nt], acc[mt][nt], 0, 0, 0);
    }

    // epilogue
    float bv[4];
    #pragma unroll
    for (int nt = 0; nt < 4; ++nt) bv[nt] = bias[n0 + wc * 64 + nt * 16 + q16];
    int colbase = n0 + wc * 64 + q16;
    #pragma unroll
    for (int mt = 0; mt < 4; ++mt) {
        #pragma unroll
        for (int r = 0; r < 4; ++r) {
            int m = m0 + wr * 64 + mt * 16 + g * 4 + r;
            size_t rowoff = ((size_t)b * M + m) * N;
            #pragma unroll
            for (int nt = 0; nt < 4; ++nt) {
                float val = acc[mt][nt][r] + bv[nt];
                if (EPI == 1) {
                    ((ushort_t*)Out)[rowoff + colbase + nt * 16] = bfc(gelu_f(val));
                } else {
                    ((float*)Out)[rowoff + colbase + nt * 16] = val;
                }
            }
        }
    }
}

// ---------------------------------------------------------------------------
// Column-norm stats: in f32 [B][L][C]; partial sums over L/SPLIT chunk.
// grid (C/64, SPLIT, B). part layout [B][SPLIT][C][2].
// ---------------------------------------------------------------------------
__global__ __launch_bounds__(256)
void cn_stats(const float* __restrict__ in, float* __restrict__ part,
              int L, int C, int SPLIT)
{
    int tid = threadIdx.x;
    int o = blockIdx.x * 64 + (tid & 63);
    int b = blockIdx.z;
    int chunk = L / SPLIT;
    int l0 = blockIdx.y * chunk;
    float s = 0.f, ss = 0.f;
    for (int l = l0 + (tid >> 6); l < l0 + chunk; l += 4) {
        float v = in[((size_t)b * L + l) * C + o];
        s += v; ss += v * v;
    }
    __shared__ float R1[4][64], R2[4][64];
    R1[tid >> 6][tid & 63] = s;
    R2[tid >> 6][tid & 63] = ss;
    __syncthreads();
    if (tid < 64) {
        float fs  = R1[0][tid] + R1[1][tid] + R1[2][tid] + R1[3][tid];
        float fss = R2[0][tid] + R2[1][tid] + R2[2][tid] + R2[3][tid];
        size_t po = ((size_t)(b * SPLIT + blockIdx.y) * C + blockIdx.x * 64 + tid) * 2;
        part[po] = fs; part[po + 1] = fss;
    }
}

// ---------------------------------------------------------------------------
// Column-norm apply. grid (C/64, L/64, B).
// MODE 0: outb bf16 [l][c].   MODE 1: (+res) -> outf f32 + outb bf16.
// MODE 2: (+res) -> outf f32 TRANSPOSED [B][C][L].
// ---------------------------------------------------------------------------
template<int MODE>
__global__ __launch_bounds__(256)
void cn_apply(const float* __restrict__ in, const float* __restrict__ part,
              const float* __restrict__ res, ushort_t* __restrict__ outb,
              float* __restrict__ outf, int L, int C, int SPLIT)
{
    __shared__ float SM[64], SR[64];
    __shared__ float T[64][65];
    int tid = threadIdx.x;
    int b = blockIdx.z;
    if (tid < 64) {
        int col = blockIdx.x * 64 + tid;
        float fs = 0.f, fss = 0.f;
        for (int sp = 0; sp < SPLIT; ++sp) {
            size_t po = ((size_t)(b * SPLIT + sp) * C + col) * 2;
            fs += part[po]; fss += part[po + 1];
        }
        float mean = fs / (float)L;
        float var = fss / (float)L - mean * mean;
        SM[tid] = mean;
        SR[tid] = rsqrtf(var + 1e-5f);
    }
    __syncthreads();

    int oc = tid & 63;
    int o = blockIdx.x * 64 + oc;
    int lr = tid >> 6;
    int l0 = blockIdx.y * 64;
    float mean = SM[oc], rstd = SR[oc];
    #pragma unroll
    for (int i = 0; i < 16; ++i) {
        int l = l0 + lr + i * 4;
        size_t idx = ((size_t)b * L + l) * C + o;
        float v = in[idx];
        float y = (v - mean) * rstd;
        if (MODE == 0) {
            outb[idx] = bfc(y);
        } else if (MODE == 1) {
            y += res[idx];
            outf[idx] = y;
            outb[idx] = bfc(y);
        } else {
            y += res[idx];
            T[lr + i * 4][oc] = y;
        }
    }
    if (MODE == 2) {
        __syncthreads();
        int ll = tid & 63;
        int orr = tid >> 6;
        #pragma unroll
        for (int i = 0; i < 16; ++i) {
            int oc2 = orr + i * 4;
            outf[((size_t)b * C + blockIdx.x * 64 + oc2) * L + l0 + ll] = T[ll][oc2];
        }
    }
}

// ---------------------------------------------------------------------------
// MFMA windowed cross attention. One block (512 thr / 8 waves) per (n, h, b).
// qT/kT/vT: bf16 [B][L][CDIM] (normalized, transposed space).
// win out: (B,NH,NWIN,WINQ,HD) f32.
// ---------------------------------------------------------------------------
__global__ __launch_bounds__(512)
void attn_win_mfma(const ushort_t* __restrict__ qT, const ushort_t* __restrict__ kT,
                   const ushort_t* __restrict__ vT, float* __restrict__ win)
{
    __shared__ __align__(16) char KB[65536];   // K: [512 kpos][64 d] bf16, off ^= (kpos&7)<<4
    __shared__ __align__(16) char VB[65536];   // V: [64 d][512 kpos] bf16, off ^= (d&7)<<4
    __shared__ uint32_t PL[8][16][20];

    int n = blockIdx.x, hh = blockIdx.y, b = blockIdx.z;
    int s = n * WSTRIDE;
    int nq = min(s + WINQ, LDD) - s;
    int es = 2 * s;
    int ne = min(2 * (s + nq), LEE) - es;

    int tid = threadIdx.x;
    int lane = tid & 63;
    int w = tid >> 6;
    int q16 = lane & 15;
    int g = lane >> 4;

    // ---- stage K via global_load_lds (pre-swizzled per-lane source) ----
    {
        const ushort_t* kbase = kT + (size_t)b * LEE * CDIM + hh * HD;
        #pragma unroll
        for (int iss = 0; iss < 8; ++iss) {
            int o = w * 8192 + iss * 1024 + lane * 16;
            int kpos = o >> 7;
            int slot = (o >> 4) & 7;
            int c8 = slot ^ (kpos & 7);
            int srow = min(es + kpos, LEE - 1);
            gload16(kbase + (size_t)srow * CDIM + c8 * 8, KB + w * 8192 + iss * 1024);
        }
    }
    // ---- stage V: transpose to [d][kpos], paired-row u32 writes ----
    {
        const ushort_t* vbase = vT + (size_t)b * LEE * CDIM + hh * HD;
        #pragma unroll
        for (int it = 0; it < 4; ++it) {
            int idx = tid + it * 512;
            int c8 = idx & 7;
            int kp = idx >> 3;            // kpos pair 0..255
            int r0 = min(es + 2 * kp, LEE - 1);
            int r1 = min(es + 2 * kp + 1, LEE - 1);
            u16x8 wa = *reinterpret_cast<const u16x8*>(vbase + (size_t)r0 * CDIM + c8 * 8);
            u16x8 wb = *reinterpret_cast<const u16x8*>(vbase + (size_t)r1 * CDIM + c8 * 8);
            #pragma unroll
            for (int j = 0; j < 8; ++j) {
                int d = c8 * 8 + j;
                uint32_t dw = (uint32_t)wa[j] | ((uint32_t)wb[j] << 16);
                int byte = d * 1024 + ((kp * 4) ^ ((d & 7) << 4));
                *reinterpret_cast<uint32_t*>(&VB[byte]) = dw;
            }
        }
    }
    __syncthreads();

    const ushort_t* qtb = qT + ((size_t)b * LDD + s) * CDIM + hh * HD;
    const size_t wbase = ((size_t)(b * NHEAD + hh) * NWIN + n) * (WINQ * HD);

    #pragma unroll 1
    for (int t = 0; t < 2; ++t) {
        int qrow_loc = w * 32 + t * 16 + q16;
        int qr = min(qrow_loc, nq - 1);

        const ushort_t* qrow = qtb + (size_t)qr * CDIM;
        bf16x8 bq[2];
        #pragma unroll
        for (int kd = 0; kd < 2; ++kd)
            bq[kd] = *reinterpret_cast<const bf16x8*>(qrow + kd * 32 + g * 8);

        f32x4 ot[4];
        #pragma unroll
        for (int dt = 0; dt < 4; ++dt) { ot[dt][0]=0.f; ot[dt][1]=0.f; ot[dt][2]=0.f; ot[dt][3]=0.f; }
        float m = -3e38f, ssum = 0.f;

        for (int cc = 0; cc < 8; ++cc) {
            // ---- S^T tiles: A = K (16 kpos x 32 d), B = Q ----
            f32x4 st[4];
            #pragma unroll
            for (int ct = 0; ct < 4; ++ct) {
                int kpos = cc * 64 + ct * 16 + q16;
                int rb = kpos * 128;
                int sw = (kpos & 7) << 4;
                bf16x8 ka0 = *reinterpret_cast<const bf16x8*>(&KB[rb + ((g * 16) ^ sw)]);
                bf16x8 ka1 = *reinterpret_cast<const bf16x8*>(&KB[rb + ((64 + g * 16) ^ sw)]);
                f32x4 z; z[0]=0.f; z[1]=0.f; z[2]=0.f; z[3]=0.f;
                z = __builtin_amdgcn_mfma_f32_16x16x32_bf16(ka0, bq[0], z, 0, 0, 0);
                z = __builtin_amdgcn_mfma_f32_16x16x32_bf16(ka1, bq[1], z, 0, 0, 0);
                st[ct] = z;
            }
            // ---- scale + mask + online max ----
            float pmax = -3e38f;
            #pragma unroll
            for (int ct = 0; ct < 4; ++ct) {
                #pragma unroll
                for (int r = 0; r < 4; ++r) {
                    int kg = cc * 64 + ct * 16 + g * 4 + r;
                    float x = (kg < ne) ? st[ct][r] * 0.125f : -1e30f;
                    st[ct][r] = x;
                    pmax = fmaxf(pmax, x);
                }
            }
            pmax = fmaxf(pmax, __shfl_xor(pmax, 16));
            pmax = fmaxf(pmax, __shfl_xor(pmax, 32));
            float mnew = fmaxf(m, pmax);
            float corr = __expf(m - mnew);
            m = mnew;
            ssum *= corr;
            #pragma unroll
            for (int dt = 0; dt < 4; ++dt) {
                ot[dt][0] *= corr; ot[dt][1] *= corr;
                ot[dt][2] *= corr; ot[dt][3] *= corr;
            }
            // ---- P = exp, pack bf16, LDS bounce to B-frag layout, PV ----
            #pragma unroll
            for (int o32 = 0; o32 < 2; ++o32) {
                #pragma unroll
                for (int ti = 0; ti < 2; ++ti) {
                    int ct = o32 * 2 + ti;
                    float p0 = __expf(st[ct][0] - m);
                    float p1 = __expf(st[ct][1] - m);
                    float p2 = __expf(st[ct][2] - m);
                    float p3 = __expf(st[ct][3] - m);
                    ssum += p0 + p1 + p2 + p3;
                    u32x2 pr; pr[0] = pack2(p0, p1); pr[1] = pack2(p2, p3);
                    *reinterpret_cast<u32x2*>(&PL[w][q16][ti * 8 + g * 2]) = pr;
                }
                bf16x8 pb = *reinterpret_cast<const bf16x8*>(&PL[w][q16][g * 4]);
                #pragma unroll
                for (int dt = 0; dt < 4; ++dt) {
                    int d = dt * 16 + q16;
                    int byte = d * 1024 + (((cc * 128 + o32 * 64 + g * 16)) ^ ((d & 7) << 4));
                    bf16x8 va = *reinterpret_cast<const bf16x8*>(&VB[byte]);
                    ot[dt] = __builtin_amdgcn_mfma_f32_16x16x32_bf16(va, pb, ot[dt], 0, 0, 0);
                }
            }
        }
        // ---- epilogue ----
        float stot = ssum + __shfl_xor(ssum, 16);
        stot += __shfl_xor(stot, 32);
        float rs = 1.f / stot;
        if (qrow_loc < nq) {
            float* wp = &win[wbase + (size_t)qrow_loc * HD];
            #pragma unroll
            for (int dt = 0; dt < 4; ++dt) {
                float4 o4 = make_float4(ot[dt][0] * rs, ot[dt][1] * rs,
                                        ot[dt][2] * rs, ot[dt][3] * rs);
                *reinterpret_cast<float4*>(&wp[dt * 16 + g * 4]) = o4;
            }
        }
    }
}

// ---------------------------------------------------------------------------
// Overlap-add + count-normalize -> bf16 [B][L][CDIM] (transposed space).
// grid (LDD/64, NHEAD, NB)
// ---------------------------------------------------------------------------
__global__ __launch_bounds__(256)
void attn_finalize(const float* __restrict__ win, ushort_t* __restrict__ outT)
{
    int l0 = blockIdx.x * 64;
    int hh = blockIdx.y, b = blockIdx.z;
    int tid = threadIdx.x;
    int d = tid & 63;
    int lq = tid >> 6;
    #pragma unroll
    for (int i = 0; i < 16; ++i) {
        int ll = lq + i * 4;
        int l = l0 + ll;
        int n1 = min(NWIN - 1, l / WSTRIDE);
        int n0 = (l >= 64) ? ((l - 64) / WSTRIDE) : 0;
        float acc = 0.f;
        for (int n = n0; n <= n1; ++n) {
            int qrow = l - n * WSTRIDE;
            acc += win[(((size_t)(b * NHEAD + hh) * NWIN + n) * WINQ + qrow) * HD + d];
        }
        float v = acc / (float)(n1 - n0 + 1);
        outT[((size_t)b * LDD + l) * CDIM + hh * HD + d] = bfc(v);
    }
}

// ---------------------------------------------------------------------------
extern "C" void kernel_launch(void* const* d_in, const int* in_sizes, int n_in,
                              void* d_out, int out_size, void* d_ws, size_t ws_size,
                              hipStream_t stream)
{
    const float* x_dec = (const float*)d_in[0];
    const float* x_enc = (const float*)d_in[1];
    const float* wq = (const float*)d_in[2];
    const float* bq = (const float*)d_in[3];
    const float* wk = (const float*)d_in[4];
    const float* bk = (const float*)d_in[5];
    const float* wv = (const float*)d_in[6];
    const float* bv = (const float*)d_in[7];
    const float* wo = (const float*)d_in[8];
    const float* bo = (const float*)d_in[9];
    const float* w1 = (const float*)d_in[10];
    const float* b1 = (const float*)d_in[11];
    const float* w2 = (const float*)d_in[12];
    const float* b2 = (const float*)d_in[13];
    float* out = (float*)d_out;

    // ---- workspace carve (bytes), total ~230 MiB ----
    char* base = (char*)d_ws;
    ushort_t* wqb = (ushort_t*)base;
    ushort_t* wkb = wqb + 262144;
    ushort_t* wvb = wkb + 131072;
    ushort_t* wob = wvb + 131072;
    ushort_t* w1b = wob + 262144;
    ushort_t* w2b = w1b + 1048576;      // ends at 5,767,168 B
    char* S1 = base + 5767168;          // 33.5 MB f32
    char* S2 = S1 + 33554432;           // 16.8 MB bf16
    char* S3 = S2 + 16777216;           // 16.8 MB bf16
    char* S4 = S3 + 16777216;           // 33.5 MB f32
    char* S5 = S4 + 33554432;           // 67 MB
    char* S6 = S5 + 67108864;           // 33.5 MB
    char* S7 = S6 + 33554432;           // 33.5 MB
    char* S8 = S7 + 33554432;           // stats partials

    float*    x_decT_f = (float*)S1;    float* y_pre   = (float*)S1;
    ushort_t* x_decT_b = (ushort_t*)S2; ushort_t* qTb  = (ushort_t*)S2;
    ushort_t* attn_outT = (ushort_t*)S2; ushort_t* xresT_b = (ushort_t*)S2;
    ushort_t* x_encT_b = (ushort_t*)S3;
    float*    q_pre = (float*)S4;
    float*    kv_pre = (float*)S5;      float* winb = (float*)S5; ushort_t* hT = (ushort_t*)S5;
    ushort_t* kTb = (ushort_t*)S6;      float* xresT_f = (float*)S6;
    ushort_t* vTb = (ushort_t*)S7;      float* xo_pre = (float*)S7;
    float*    part = (float*)S8;

    dim3 blk(256);
    const int SPLIT = 16;

    // 0. weights -> bf16
    cvt_bf16<<<dim3(256), blk, 0, stream>>>(wq, wqb, 262144);
    cvt_bf16<<<dim3(128), blk, 0, stream>>>(wk, wkb, 131072);
    cvt_bf16<<<dim3(128), blk, 0, stream>>>(wv, wvb, 131072);
    cvt_bf16<<<dim3(256), blk, 0, stream>>>(wo, wob, 262144);
    cvt_bf16<<<dim3(1024), blk, 0, stream>>>(w1, w1b, 1048576);
    cvt_bf16<<<dim3(1024), blk, 0, stream>>>(w2, w2b, 1048576);

    // 1. transpose inputs to [B][L][C]
    tcvt<1><<<dim3(LDD / 64, CDIM / 64, NB), blk, 0, stream>>>(x_dec, x_decT_b, x_decT_f, CDIM, LDD);
    tcvt<0><<<dim3(LEE / 64, CENC / 64, NB), blk, 0, stream>>>(x_enc, x_encT_b, nullptr, CENC, LEE);

    // 2. q = IN(x_decT @ wq^T)
    mgemm<0><<<dim3(CDIM / 128, LDD / 128, NB), blk, 0, stream>>>(x_decT_b, wqb, bq, q_pre, LDD, CDIM, CDIM);
    cn_stats<<<dim3(CDIM / 64, SPLIT, NB), blk, 0, stream>>>(q_pre, part, LDD, CDIM, SPLIT);
    cn_apply<0><<<dim3(CDIM / 64, LDD / 64, NB), blk, 0, stream>>>(q_pre, part, nullptr, qTb, nullptr, LDD, CDIM, SPLIT);

    // 3. k = IN(x_encT @ wk^T)
    mgemm<0><<<dim3(CDIM / 128, LEE / 128, NB), blk, 0, stream>>>(x_encT_b, wkb, bk, kv_pre, LEE, CDIM, CENC);
    cn_stats<<<dim3(CDIM / 64, SPLIT, NB), blk, 0, stream>>>(kv_pre, part, LEE, CDIM, SPLIT);
    cn_apply<0><<<dim3(CDIM / 64, LEE / 64, NB), blk, 0, stream>>>(kv_pre, part, nullptr, kTb, nullptr, LEE, CDIM, SPLIT);

    // 4. v = IN(x_encT @ wv^T)
    mgemm<0><<<dim3(CDIM / 128, LEE / 128, NB), blk, 0, stream>>>(x_encT_b, wvb, bv, kv_pre, LEE, CDIM, CENC);
    cn_stats<<<dim3(CDIM / 64, SPLIT, NB), blk, 0, stream>>>(kv_pre, part, LEE, CDIM, SPLIT);
    cn_apply<0><<<dim3(CDIM / 64, LEE / 64, NB), blk, 0, stream>>>(kv_pre, part, nullptr, vTb, nullptr, LEE, CDIM, SPLIT);

    // 5. windowed attention + overlap-add
    attn_win_mfma<<<dim3(NWIN, NHEAD, NB), dim3(512), 0, stream>>>(qTb, kTb, vTb, winb);
    attn_finalize<<<dim3(LDD / 64, NHEAD, NB), blk, 0, stream>>>(winb, attn_outT);

    // 6. xres = IN(attn_outT @ wo^T) + x_dec
    mgemm<0><<<dim3(CDIM / 128, LDD / 128, NB), blk, 0, stream>>>(attn_outT, wob, bo, xo_pre, LDD, CDIM, CDIM);
    cn_stats<<<dim3(CDIM / 64, SPLIT, NB), blk, 0, stream>>>(xo_pre, part, LDD, CDIM, SPLIT);
    cn_apply<1><<<dim3(CDIM / 64, LDD / 64, NB), blk, 0, stream>>>(xo_pre, part, x_decT_f, xresT_b, xresT_f, LDD, CDIM, SPLIT);

    // 7. h = gelu(xres @ w1^T)  (bf16 out)
    mgemm<1><<<dim3(HDIM / 128, LDD / 128, NB), blk, 0, stream>>>(xresT_b, w1b, b1, hT, LDD, HDIM, CDIM);

    // 8. y = IN(h @ w2^T) + xres  -> transposed write to d_out [B][C][L]
    mgemm<0><<<dim3(CDIM / 128, LDD / 128, NB), blk, 0, stream>>>(hT, w2b, b2, y_pre, LDD, CDIM, HDIM);
    cn_stats<<<dim3(CDIM / 64, SPLIT, NB), blk, 0, stream>>>(y_pre, part, LDD, CDIM, SPLIT);
    cn_apply<2><<<dim3(CDIM / 64, LDD / 64, NB), blk, 0, stream>>>(y_pre, part, xresT_f, nullptr, out, LDD, CDIM, SPLIT);

    (void)in_sizes; (void)n_in; (void)out_size; (void)ws_size;
}

// Round 4
// 452.148 us; speedup vs baseline: 6.8667x; 1.2728x over previous
//
#include <hip/hip_runtime.h>
#include <hip/hip_bf16.h>
#include <math.h>
#include <stdint.h>

#define LDD 4096
#define LEE 8192
#define CDIM 512
#define CENC 256
#define HDIM 2048
#define NB 4
#define NHEAD 8
#define HD 64
#define NWIN 22
#define WINQ 256
#define WSTRIDE 192

typedef __attribute__((ext_vector_type(8))) short bf16x8;
typedef __attribute__((ext_vector_type(8))) unsigned short u16x8;
typedef __attribute__((ext_vector_type(4))) float f32x4;
typedef __attribute__((ext_vector_type(2))) unsigned int u32x2;
typedef unsigned short ushort_t;

__device__ __forceinline__ uint32_t pack2(float lo, float hi) {
    return ((__float_as_uint(hi) + 0x8000u) & 0xffff0000u) |
           ((__float_as_uint(lo) + 0x8000u) >> 16);
}
__device__ __forceinline__ ushort_t bfc(float x) {
    return (ushort_t)((__float_as_uint(x) + 0x8000u) >> 16);
}
__device__ __forceinline__ float bf2f(ushort_t u) {
    return __uint_as_float(((uint32_t)u) << 16);
}
__device__ __forceinline__ void gload16(const void* g, void* l) {
    __builtin_amdgcn_global_load_lds(
        (const __attribute__((address_space(1))) void*)g,
        (__attribute__((address_space(3))) void*)l, 16, 0, 0);
}
// fast erf-based gelu (A&S 7.1.26, |eps| <= 1.5e-7)
__device__ __forceinline__ float gelu_fast(float x) {
    float z = fabsf(x) * 0.70710678f;
    float t = 1.0f / fmaf(0.3275911f, z, 1.0f);
    float p = t * fmaf(t, fmaf(t, fmaf(t, fmaf(t, 1.061405429f, -1.453152027f),
                                        1.421413741f), -0.284496736f), 0.254829592f);
    float e = __expf(-z * z);
    float erfz = fmaf(-p, e, 1.0f);
    float sgn = copysignf(erfz, x);
    return 0.5f * x * (1.0f + sgn);
}

// ---------------------------------------------------------------------------
// Weights f32 -> bf16, 6 segments in one launch. grid (1024, 6).
// ---------------------------------------------------------------------------
struct Cvt6Args {
    const float* src[6];
    ushort_t* dst[6];
    int n[6];
};
__global__ __launch_bounds__(256)
void cvt6(Cvt6Args a)
{
    int seg = blockIdx.y;
    int i = (blockIdx.x * 256 + threadIdx.x) * 4;
    if (i < a.n[seg]) {
        float4 v = *reinterpret_cast<const float4*>(&a.src[seg][i]);
        u32x2 p; p[0] = pack2(v.x, v.y); p[1] = pack2(v.z, v.w);
        *reinterpret_cast<u32x2*>(&a.dst[seg][i]) = p;
    }
}

// ---------------------------------------------------------------------------
// Transpose+convert: f32 [B][C][L] -> bf16 [B][L][C]. grid (L/64, C/64, B)
// ---------------------------------------------------------------------------
__global__ __launch_bounds__(256)
void tcvt(const float* __restrict__ in, ushort_t* __restrict__ outb, int C, int L)
{
    __shared__ float T[64][65];
    int l0 = blockIdx.x * 64, c0 = blockIdx.y * 64, b = blockIdx.z;
    int tid = threadIdx.x;
    int ll = tid & 63, cq = tid >> 6;
    #pragma unroll
    for (int i = 0; i < 16; ++i) {
        int c = cq + i * 4;
        T[c][ll] = in[((size_t)b * C + c0 + c) * L + l0 + ll];
    }
    __syncthreads();
    int cc = tid & 63, lq = tid >> 6;
    #pragma unroll
    for (int i = 0; i < 16; ++i) {
        int l = lq + i * 4;
        outb[((size_t)b * L + l0 + l) * C + c0 + cc] = bfc(T[cc][l]);
    }
}

// ---------------------------------------------------------------------------
// MFMA GEMM (2-phase prefetch, BK=64): Out[b][m][n] = ep(sum_k A[m][k]W[n][k]+bias[n])
// A bf16 [B][M][K], W bf16 [N][K], Out bf16 [B][M][N].
// EPI: 0 none, 1 fast-gelu. STATS: per-column (n) partial sums over the 128
// m-rows of this block -> part[b][mb][n]{s,ss} for fused instance-norm stats.
// 128x128 tile, 256 thr / 4 waves (2x2), swapped operands so each lane owns
// 4 consecutive n per acc -> packed 8B stores.
// ---------------------------------------------------------------------------
template<int EPI, int STATS>
__global__ __launch_bounds__(256)
void mgemm2(const ushort_t* __restrict__ A, const ushort_t* __restrict__ Wt,
            const float* __restrict__ bias, ushort_t* __restrict__ Out,
            float* __restrict__ part, int M, int N, int K)
{
    __shared__ __align__(16) ushort_t As[2][8192];   // 128 x 64 per buf, swizzled
    __shared__ __align__(16) ushort_t Bs[2][8192];

    int Nt = gridDim.x;
    int flat = blockIdx.y * Nt + blockIdx.x;
    int nwg = Nt * gridDim.y;
    int swz = (flat & 7) * (nwg >> 3) + (flat >> 3);   // nwg % 8 == 0 for all shapes
    int nb = swz % Nt, mb = swz / Nt;
    int b = blockIdx.z;
    int m0 = mb * 128, n0 = nb * 128;

    int tid = threadIdx.x;
    int lane = tid & 63;
    int w = tid >> 6;
    int q16 = lane & 15, g = lane >> 4;
    int wr = w >> 1, wc = w & 1;

    // pre-swizzled per-lane global sources (linear LDS dest, inverse-swz source)
    const ushort_t* Ag[4]; const ushort_t* Wg[4];
    #pragma unroll
    for (int i = 0; i < 4; ++i) {
        int gran = w * 256 + i * 64 + lane;      // 16B granule index
        int row = gran >> 3;
        int c8 = (gran & 7) ^ (row & 7);
        Ag[i] = A + ((size_t)b * M + m0 + row) * K + c8 * 8;
        Wg[i] = Wt + ((size_t)(n0 + row)) * K + c8 * 8;
    }

    f32x4 acc[4][4];
    #pragma unroll
    for (int mt = 0; mt < 4; ++mt)
        #pragma unroll
        for (int nt = 0; nt < 4; ++nt) {
            acc[mt][nt][0] = 0.f; acc[mt][nt][1] = 0.f;
            acc[mt][nt][2] = 0.f; acc[mt][nt][3] = 0.f;
        }

    // prologue: stage K-tile 0 into buf 0
    #pragma unroll
    for (int i = 0; i < 4; ++i) {
        gload16(Ag[i], &As[0][w * 2048 + i * 512]);
        gload16(Wg[i], &Bs[0][w * 2048 + i * 512]);
    }

    int NTILES = K >> 6;
    for (int kt = 0; kt < NTILES; ++kt) {
        int cur = kt & 1;
        __syncthreads();                          // buf cur ready; buf cur^1 free
        if (kt + 1 < NTILES) {
            int k0 = (kt + 1) << 6;
            #pragma unroll
            for (int i = 0; i < 4; ++i) {
                gload16(Ag[i] + k0, &As[cur ^ 1][w * 2048 + i * 512]);
                gload16(Wg[i] + k0, &Bs[cur ^ 1][w * 2048 + i * 512]);
            }
        }
        const char* Ab = (const char*)&As[cur][0];
        const char* Bb = (const char*)&Bs[cur][0];
        bf16x8 ka[4][2], kb[4][2];
        #pragma unroll
        for (int mt = 0; mt < 4; ++mt) {
            int r = wr * 64 + mt * 16 + q16;
            int rb = r * 128;
            int sw8 = (r & 7) << 4;
            ka[mt][0] = *reinterpret_cast<const bf16x8*>(Ab + rb + ((g * 16) ^ sw8));
            ka[mt][1] = *reinterpret_cast<const bf16x8*>(Ab + rb + ((64 + g * 16) ^ sw8));
        }
        #pragma unroll
        for (int nt = 0; nt < 4; ++nt) {
            int r = wc * 64 + nt * 16 + q16;
            int rb = r * 128;
            int sw8 = (r & 7) << 4;
            kb[nt][0] = *reinterpret_cast<const bf16x8*>(Bb + rb + ((g * 16) ^ sw8));
            kb[nt][1] = *reinterpret_cast<const bf16x8*>(Bb + rb + ((64 + g * 16) ^ sw8));
        }
        #pragma unroll
        for (int mt = 0; mt < 4; ++mt)
            #pragma unroll
            for (int nt = 0; nt < 4; ++nt) {
                acc[mt][nt] = __builtin_amdgcn_mfma_f32_16x16x32_bf16(kb[nt][0], ka[mt][0], acc[mt][nt], 0, 0, 0);
                acc[mt][nt] = __builtin_amdgcn_mfma_f32_16x16x32_bf16(kb[nt][1], ka[mt][1], acc[mt][nt], 0, 0, 0);
            }
    }

    // epilogue: D row=(g*4+reg) -> n, col=q16 -> m (operands swapped)
    float4 bv4[4];
    #pragma unroll
    for (int nt = 0; nt < 4; ++nt)
        bv4[nt] = *reinterpret_cast<const float4*>(&bias[n0 + wc * 64 + nt * 16 + g * 4]);

    float s_[4][4], q_[4][4];
    if (STATS) {
        #pragma unroll
        for (int nt = 0; nt < 4; ++nt)
            #pragma unroll
            for (int r = 0; r < 4; ++r) { s_[nt][r] = 0.f; q_[nt][r] = 0.f; }
    }

    #pragma unroll
    for (int mt = 0; mt < 4; ++mt) {
        int m = m0 + wr * 64 + mt * 16 + q16;
        size_t rowoff = ((size_t)b * M + m) * N;
        #pragma unroll
        for (int nt = 0; nt < 4; ++nt) {
            float vv[4];
            #pragma unroll
            for (int r = 0; r < 4; ++r) {
                float val = acc[mt][nt][r] + ((const float*)&bv4[nt])[r];
                if (EPI == 1) val = gelu_fast(val);
                if (STATS) { s_[nt][r] += val; q_[nt][r] = fmaf(val, val, q_[nt][r]); }
                vv[r] = val;
            }
            u32x2 pk; pk[0] = pack2(vv[0], vv[1]); pk[1] = pack2(vv[2], vv[3]);
            *reinterpret_cast<u32x2*>(&Out[rowoff + n0 + wc * 64 + nt * 16 + g * 4]) = pk;
        }
    }

    if (STATS) {
        __syncthreads();
        float* SS = (float*)&As[0][0];   // [128][33]
        float* SQ = (float*)&Bs[0][0];
        #pragma unroll
        for (int nt = 0; nt < 4; ++nt)
            #pragma unroll
            for (int r = 0; r < 4; ++r) {
                int nl = wc * 64 + nt * 16 + g * 4 + r;
                SS[nl * 33 + wr * 16 + q16] = s_[nt][r];
                SQ[nl * 33 + wr * 16 + q16] = q_[nt][r];
            }
        __syncthreads();
        if (tid < 128) {
            float ts = 0.f, tq = 0.f;
            #pragma unroll 8
            for (int j = 0; j < 32; ++j) { ts += SS[tid * 33 + j]; tq += SQ[tid * 33 + j]; }
            size_t po = (((size_t)b * (M >> 7) + mb) * N + n0 + tid) * 2;
            part[po] = ts; part[po + 1] = tq;
        }
    }
}

// ---------------------------------------------------------------------------
// Column-norm apply (vectorized, bf16 in/out, C=512). grid (L/16, 1, B).
// out[l][c] = (in[l][c]-mean_c)*rstd_c (+ res[l][c] if RES). In-place safe.
// ---------------------------------------------------------------------------
template<int RES>
__global__ __launch_bounds__(256)
void cn_apply_v(const ushort_t* __restrict__ in, const float* __restrict__ part,
                const ushort_t* __restrict__ res, ushort_t* __restrict__ out,
                int L, int SPLITM)
{
    __shared__ float SM[CDIM], SR[CDIM];
    int b = blockIdx.z;
    int tid = threadIdx.x;
    for (int c = tid; c < CDIM; c += 256) {
        float fs = 0.f, fq = 0.f;
        for (int sp = 0; sp < SPLITM; ++sp) {
            size_t po = (((size_t)b * SPLITM + sp) * CDIM + c) * 2;
            fs += part[po]; fq += part[po + 1];
        }
        float mean = fs / (float)L;
        float var = fq / (float)L - mean * mean;
        SM[c] = mean; SR[c] = rsqrtf(var + 1e-5f);
    }
    __syncthreads();
    int c0 = (tid & 63) * 8;
    int l0 = blockIdx.x * 16 + (tid >> 6) * 4;
    float mm[8], rr[8];
    #pragma unroll
    for (int j = 0; j < 8; ++j) { mm[j] = SM[c0 + j]; rr[j] = SR[c0 + j]; }
    #pragma unroll
    for (int i = 0; i < 4; ++i) {
        int l = l0 + i;
        size_t off = ((size_t)b * L + l) * CDIM + c0;
        u16x8 v = *reinterpret_cast<const u16x8*>(in + off);
        u16x8 rv;
        if (RES) rv = *reinterpret_cast<const u16x8*>(res + off);
        u16x8 o;
        #pragma unroll
        for (int j = 0; j < 8; ++j) {
            float y = (bf2f((ushort_t)v[j]) - mm[j]) * rr[j];
            if (RES) y += bf2f((ushort_t)rv[j]);
            o[j] = bfc(y);
        }
        *reinterpret_cast<u16x8*>(out + off) = o;
    }
}

// ---------------------------------------------------------------------------
// Final: out[B][C][L] f32 = norm(in)[l][c] + res[l][c], transposed write.
// grid (C/64, L/64, B).
// ---------------------------------------------------------------------------
__global__ __launch_bounds__(256)
void cn_apply_t(const ushort_t* __restrict__ in, const float* __restrict__ part,
                const ushort_t* __restrict__ res, float* __restrict__ outf,
                int L, int SPLITM)
{
    __shared__ float SM[64], SR[64];
    __shared__ float T[64][65];
    int b = blockIdx.z;
    int c0 = blockIdx.x * 64;
    int l0 = blockIdx.y * 64;
    int tid = threadIdx.x;
    if (tid < 64) {
        int c = c0 + tid;
        float fs = 0.f, fq = 0.f;
        for (int sp = 0; sp < SPLITM; ++sp) {
            size_t po = (((size_t)b * SPLITM + sp) * CDIM + c) * 2;
            fs += part[po]; fq += part[po + 1];
        }
        float mean = fs / (float)L;
        float var = fq / (float)L - mean * mean;
        SM[tid] = mean; SR[tid] = rsqrtf(var + 1e-5f);
    }
    __syncthreads();
    int cc = tid & 63;
    int lq = tid >> 6;
    float mean = SM[cc], rstd = SR[cc];
    #pragma unroll
    for (int i = 0; i < 16; ++i) {
        int l = l0 + lq + i * 4;
        size_t idx = ((size_t)b * L + l) * CDIM + c0 + cc;
        T[lq + i * 4][cc] = (bf2f(in[idx]) - mean) * rstd + bf2f(res[idx]);
    }
    __syncthreads();
    int ll = tid & 63;
    int cr = tid >> 6;
    #pragma unroll
    for (int i = 0; i < 16; ++i) {
        int c = cr + i * 4;
        outf[((size_t)b * CDIM + c0 + c) * L + l0 + ll] = T[ll][c];
    }
}

// ---------------------------------------------------------------------------
// MFMA windowed cross attention. One block (512 thr / 8 waves) per (n, h, b).
// qT/kT/vT: bf16 [B][L][CDIM]. win out: (B,NH,NWIN,WINQ,HD) f32.
// ---------------------------------------------------------------------------
__global__ __launch_bounds__(512)
void attn_win_mfma(const ushort_t* __restrict__ qT, const ushort_t* __restrict__ kT,
                   const ushort_t* __restrict__ vT, float* __restrict__ win)
{
    __shared__ __align__(16) char KB[65536];   // K: [512 kpos][64 d] bf16, off ^= (kpos&7)<<4
    __shared__ __align__(16) char VB[65536];   // V: [64 d][512 kpos] bf16, off ^= (d&7)<<4
    __shared__ uint32_t PL[8][16][20];

    int n = blockIdx.x, hh = blockIdx.y, b = blockIdx.z;
    int s = n * WSTRIDE;
    int nq = min(s + WINQ, LDD) - s;
    int es = 2 * s;
    int ne = min(2 * (s + nq), LEE) - es;

    int tid = threadIdx.x;
    int lane = tid & 63;
    int w = tid >> 6;
    int q16 = lane & 15;
    int g = lane >> 4;

    // ---- stage K via global_load_lds (pre-swizzled per-lane source) ----
    {
        const ushort_t* kbase = kT + (size_t)b * LEE * CDIM + hh * HD;
        #pragma unroll
        for (int iss = 0; iss < 8; ++iss) {
            int o = w * 8192 + iss * 1024 + lane * 16;
            int kpos = o >> 7;
            int slot = (o >> 4) & 7;
            int c8 = slot ^ (kpos & 7);
            int srow = min(es + kpos, LEE - 1);
            gload16(kbase + (size_t)srow * CDIM + c8 * 8, KB + w * 8192 + iss * 1024);
        }
    }
    // ---- stage V: transpose to [d][kpos], paired-row u32 writes ----
    {
        const ushort_t* vbase = vT + (size_t)b * LEE * CDIM + hh * HD;
        #pragma unroll
        for (int it = 0; it < 4; ++it) {
            int idx = tid + it * 512;
            int c8 = idx & 7;
            int kp = idx >> 3;
            int r0 = min(es + 2 * kp, LEE - 1);
            int r1 = min(es + 2 * kp + 1, LEE - 1);
            u16x8 wa = *reinterpret_cast<const u16x8*>(vbase + (size_t)r0 * CDIM + c8 * 8);
            u16x8 wb = *reinterpret_cast<const u16x8*>(vbase + (size_t)r1 * CDIM + c8 * 8);
            #pragma unroll
            for (int j = 0; j < 8; ++j) {
                int d = c8 * 8 + j;
                uint32_t dw = (uint32_t)wa[j] | ((uint32_t)wb[j] << 16);
                int byte = d * 1024 + ((kp * 4) ^ ((d & 7) << 4));
                *reinterpret_cast<uint32_t*>(&VB[byte]) = dw;
            }
        }
    }
    __syncthreads();

    const ushort_t* qtb = qT + ((size_t)b * LDD + s) * CDIM + hh * HD;
    const size_t wbase = ((size_t)(b * NHEAD + hh) * NWIN + n) * (WINQ * HD);

    #pragma unroll 1
    for (int t = 0; t < 2; ++t) {
        int qrow_loc = w * 32 + t * 16 + q16;
        int qr = min(qrow_loc, nq - 1);

        const ushort_t* qrow = qtb + (size_t)qr * CDIM;
        bf16x8 bq[2];
        #pragma unroll
        for (int kd = 0; kd < 2; ++kd)
            bq[kd] = *reinterpret_cast<const bf16x8*>(qrow + kd * 32 + g * 8);

        f32x4 ot[4];
        #pragma unroll
        for (int dt = 0; dt < 4; ++dt) { ot[dt][0]=0.f; ot[dt][1]=0.f; ot[dt][2]=0.f; ot[dt][3]=0.f; }
        float m = -3e38f, ssum = 0.f;

        for (int cc = 0; cc < 8; ++cc) {
            f32x4 st[4];
            #pragma unroll
            for (int ct = 0; ct < 4; ++ct) {
                int kpos = cc * 64 + ct * 16 + q16;
                int rb = kpos * 128;
                int sw = (kpos & 7) << 4;
                bf16x8 ka0 = *reinterpret_cast<const bf16x8*>(&KB[rb + ((g * 16) ^ sw)]);
                bf16x8 ka1 = *reinterpret_cast<const bf16x8*>(&KB[rb + ((64 + g * 16) ^ sw)]);
                f32x4 z; z[0]=0.f; z[1]=0.f; z[2]=0.f; z[3]=0.f;
                z = __builtin_amdgcn_mfma_f32_16x16x32_bf16(ka0, bq[0], z, 0, 0, 0);
                z = __builtin_amdgcn_mfma_f32_16x16x32_bf16(ka1, bq[1], z, 0, 0, 0);
                st[ct] = z;
            }
            float pmax = -3e38f;
            #pragma unroll
            for (int ct = 0; ct < 4; ++ct) {
                #pragma unroll
                for (int r = 0; r < 4; ++r) {
                    int kg = cc * 64 + ct * 16 + g * 4 + r;
                    float x = (kg < ne) ? st[ct][r] * 0.125f : -1e30f;
                    st[ct][r] = x;
                    pmax = fmaxf(pmax, x);
                }
            }
            pmax = fmaxf(pmax, __shfl_xor(pmax, 16));
            pmax = fmaxf(pmax, __shfl_xor(pmax, 32));
            float mnew = fmaxf(m, pmax);
            float corr = __expf(m - mnew);
            m = mnew;
            ssum *= corr;
            #pragma unroll
            for (int dt = 0; dt < 4; ++dt) {
                ot[dt][0] *= corr; ot[dt][1] *= corr;
                ot[dt][2] *= corr; ot[dt][3] *= corr;
            }
            #pragma unroll
            for (int o32 = 0; o32 < 2; ++o32) {
                #pragma unroll
                for (int ti = 0; ti < 2; ++ti) {
                    int ct = o32 * 2 + ti;
                    float p0 = __expf(st[ct][0] - m);
                    float p1 = __expf(st[ct][1] - m);
                    float p2 = __expf(st[ct][2] - m);
                    float p3 = __expf(st[ct][3] - m);
                    ssum += p0 + p1 + p2 + p3;
                    u32x2 pr; pr[0] = pack2(p0, p1); pr[1] = pack2(p2, p3);
                    *reinterpret_cast<u32x2*>(&PL[w][q16][ti * 8 + g * 2]) = pr;
                }
                bf16x8 pb = *reinterpret_cast<const bf16x8*>(&PL[w][q16][g * 4]);
                #pragma unroll
                for (int dt = 0; dt < 4; ++dt) {
                    int d = dt * 16 + q16;
                    int byte = d * 1024 + (((cc * 128 + o32 * 64 + g * 16)) ^ ((d & 7) << 4));
                    bf16x8 va = *reinterpret_cast<const bf16x8*>(&VB[byte]);
                    ot[dt] = __builtin_amdgcn_mfma_f32_16x16x32_bf16(va, pb, ot[dt], 0, 0, 0);
                }
            }
        }
        float stot = ssum + __shfl_xor(ssum, 16);
        stot += __shfl_xor(stot, 32);
        float rs = 1.f / stot;
        if (qrow_loc < nq) {
            float* wp = &win[wbase + (size_t)qrow_loc * HD];
            #pragma unroll
            for (int dt = 0; dt < 4; ++dt) {
                float4 o4 = make_float4(ot[dt][0] * rs, ot[dt][1] * rs,
                                        ot[dt][2] * rs, ot[dt][3] * rs);
                *reinterpret_cast<float4*>(&wp[dt * 16 + g * 4]) = o4;
            }
        }
    }
}

// ---------------------------------------------------------------------------
// Overlap-add + count-normalize -> bf16 [B][L][CDIM]. grid (LDD/64, NHEAD, NB)
// ---------------------------------------------------------------------------
__global__ __launch_bounds__(256)
void attn_finalize(const float* __restrict__ win, ushort_t* __restrict__ outT)
{
    int l0 = blockIdx.x * 64;
    int hh = blockIdx.y, b = blockIdx.z;
    int tid = threadIdx.x;
    int d = tid & 63;
    int lq = tid >> 6;
    #pragma unroll
    for (int i = 0; i < 16; ++i) {
        int ll = lq + i * 4;
        int l = l0 + ll;
        int n1 = min(NWIN - 1, l / WSTRIDE);
        int n0 = (l >= 64) ? ((l - 64) / WSTRIDE) : 0;
        float acc = 0.f;
        for (int n = n0; n <= n1; ++n) {
            int qrow = l - n * WSTRIDE;
            acc += win[(((size_t)(b * NHEAD + hh) * NWIN + n) * WINQ + qrow) * HD + d];
        }
        float v = acc / (float)(n1 - n0 + 1);
        outT[((size_t)b * LDD + l) * CDIM + hh * HD + d] = bfc(v);
    }
}

// ---------------------------------------------------------------------------
extern "C" void kernel_launch(void* const* d_in, const int* in_sizes, int n_in,
                              void* d_out, int out_size, void* d_ws, size_t ws_size,
                              hipStream_t stream)
{
    const float* x_dec = (const float*)d_in[0];
    const float* x_enc = (const float*)d_in[1];
    const float* wq = (const float*)d_in[2];
    const float* bq = (const float*)d_in[3];
    const float* wk = (const float*)d_in[4];
    const float* bk = (const float*)d_in[5];
    const float* wv = (const float*)d_in[6];
    const float* bv = (const float*)d_in[7];
    const float* wo = (const float*)d_in[8];
    const float* bo = (const float*)d_in[9];
    const float* w1 = (const float*)d_in[10];
    const float* b1 = (const float*)d_in[11];
    const float* w2 = (const float*)d_in[12];
    const float* b2 = (const float*)d_in[13];
    float* out = (float*)d_out;

    // ---- workspace carve (bytes), ~162.5 MiB peak with aliasing ----
    char* base = (char*)d_ws;
    ushort_t* wqb = (ushort_t*)(base);
    ushort_t* wkb = (ushort_t*)(base + 524288);
    ushort_t* wvb = (ushort_t*)(base + 786432);
    ushort_t* wob = (ushort_t*)(base + 1048576);
    ushort_t* w1b = (ushort_t*)(base + 1572864);
    ushort_t* w2b = (ushort_t*)(base + 3670016);
    ushort_t* x_decT_b = (ushort_t*)(base + 5767168);    // 16.8 MB, live -> stage6
    ushort_t* q_pre    = (ushort_t*)(base + 22544384);   // 16.8 MB -> xo_pre/xres
    ushort_t* k_pre    = (ushort_t*)(base + 39321600);   // 33.5 MB -> hT (with v)
    ushort_t* v_pre    = (ushort_t*)(base + 72876032);   // 33.5 MB
    ushort_t* x_encT_b = (ushort_t*)(base + 106430464);  // 16.8 MB -> attn_outT
    float*    winb     = (float*)(base + 123207680);     // 46.1 MB -> y_pre
    float*    part     = (float*)(base + 169345024);     // 1 MB
    ushort_t* attn_outT = x_encT_b;
    ushort_t* xo_pre   = q_pre;         // also xresT after norm (in-place)
    ushort_t* hT       = k_pre;         // spans k_pre + v_pre = 67 MB exactly
    ushort_t* y_pre    = (ushort_t*)winb;

    dim3 blk(256);

    // 0. weights -> bf16 (one launch)
    Cvt6Args ca;
    ca.src[0] = wq; ca.src[1] = wk; ca.src[2] = wv;
    ca.src[3] = wo; ca.src[4] = w1; ca.src[5] = w2;
    ca.dst[0] = wqb; ca.dst[1] = wkb; ca.dst[2] = wvb;
    ca.dst[3] = wob; ca.dst[4] = w1b; ca.dst[5] = w2b;
    ca.n[0] = 262144; ca.n[1] = 131072; ca.n[2] = 131072;
    ca.n[3] = 262144; ca.n[4] = 1048576; ca.n[5] = 1048576;
    cvt6<<<dim3(1024, 6), blk, 0, stream>>>(ca);

    // 1. transpose inputs to [B][L][C] bf16
    tcvt<<<dim3(LDD / 64, CDIM / 64, NB), blk, 0, stream>>>(x_dec, x_decT_b, CDIM, LDD);
    tcvt<<<dim3(LEE / 64, CENC / 64, NB), blk, 0, stream>>>(x_enc, x_encT_b, CENC, LEE);

    // 2. q = IN(x_decT @ wq^T + bq)
    mgemm2<0,1><<<dim3(CDIM / 128, LDD / 128, NB), blk, 0, stream>>>(x_decT_b, wqb, bq, q_pre, part, LDD, CDIM, CDIM);
    cn_apply_v<0><<<dim3(LDD / 16, 1, NB), blk, 0, stream>>>(q_pre, part, nullptr, q_pre, LDD, LDD / 128);

    // 3. k
    mgemm2<0,1><<<dim3(CDIM / 128, LEE / 128, NB), blk, 0, stream>>>(x_encT_b, wkb, bk, k_pre, part, LEE, CDIM, CENC);
    cn_apply_v<0><<<dim3(LEE / 16, 1, NB), blk, 0, stream>>>(k_pre, part, nullptr, k_pre, LEE, LEE / 128);

    // 4. v
    mgemm2<0,1><<<dim3(CDIM / 128, LEE / 128, NB), blk, 0, stream>>>(x_encT_b, wvb, bv, v_pre, part, LEE, CDIM, CENC);
    cn_apply_v<0><<<dim3(LEE / 16, 1, NB), blk, 0, stream>>>(v_pre, part, nullptr, v_pre, LEE, LEE / 128);

    // 5. windowed attention + overlap-add
    attn_win_mfma<<<dim3(NWIN, NHEAD, NB), dim3(512), 0, stream>>>(q_pre, k_pre, v_pre, winb);
    attn_finalize<<<dim3(LDD / 64, NHEAD, NB), blk, 0, stream>>>(winb, attn_outT);

    // 6. xres = IN(attn_outT @ wo^T + bo) + x_decT
    mgemm2<0,1><<<dim3(CDIM / 128, LDD / 128, NB), blk, 0, stream>>>(attn_outT, wob, bo, xo_pre, part, LDD, CDIM, CDIM);
    cn_apply_v<1><<<dim3(LDD / 16, 1, NB), blk, 0, stream>>>(xo_pre, part, x_decT_b, xo_pre, LDD, LDD / 128);

    // 7. h = gelu(xres @ w1^T + b1)
    mgemm2<1,0><<<dim3(HDIM / 128, LDD / 128, NB), blk, 0, stream>>>(xo_pre, w1b, b1, hT, nullptr, LDD, HDIM, CDIM);

    // 8. y = IN(h @ w2^T + b2) + xres -> f32 [B][C][L]
    mgemm2<0,1><<<dim3(CDIM / 128, LDD / 128, NB), blk, 0, stream>>>(hT, w2b, b2, y_pre, part, LDD, CDIM, HDIM);
    cn_apply_t<<<dim3(CDIM / 64, LDD / 64, NB), blk, 0, stream>>>(y_pre, part, xo_pre, out, LDD, LDD / 128);

    (void)in_sizes; (void)n_in; (void)out_size; (void)ws_size;
}

// Round 5
// 439.120 us; speedup vs baseline: 7.0704x; 1.0297x over previous
//
#include <hip/hip_runtime.h>
#include <hip/hip_bf16.h>
#include <math.h>
#include <stdint.h>

#define LDD 4096
#define LEE 8192
#define CDIM 512
#define CENC 256
#define HDIM 2048
#define NB 4
#define NHEAD 8
#define HD 64
#define NWIN 22
#define WINQ 256
#define WSTRIDE 192

typedef __attribute__((ext_vector_type(8))) short bf16x8;
typedef __attribute__((ext_vector_type(8))) unsigned short u16x8;
typedef __attribute__((ext_vector_type(4))) float f32x4;
typedef __attribute__((ext_vector_type(16))) float f32x16;
typedef __attribute__((ext_vector_type(2))) unsigned int u32x2;
typedef __attribute__((ext_vector_type(4))) unsigned int u32x4;
typedef unsigned short ushort_t;

__device__ __forceinline__ uint32_t pack2(float lo, float hi) {
    return ((__float_as_uint(hi) + 0x8000u) & 0xffff0000u) |
           ((__float_as_uint(lo) + 0x8000u) >> 16);
}
__device__ __forceinline__ ushort_t bfc(float x) {
    return (ushort_t)((__float_as_uint(x) + 0x8000u) >> 16);
}
__device__ __forceinline__ float bf2f(ushort_t u) {
    return __uint_as_float(((uint32_t)u) << 16);
}
__device__ __forceinline__ void gload16(const void* g, void* l) {
    __builtin_amdgcn_global_load_lds(
        (const __attribute__((address_space(1))) void*)g,
        (__attribute__((address_space(3))) void*)l, 16, 0, 0);
}
// fast erf-based gelu (A&S 7.1.26, |eps| <= 1.5e-7)
__device__ __forceinline__ float gelu_fast(float x) {
    float z = fabsf(x) * 0.70710678f;
    float t = 1.0f / fmaf(0.3275911f, z, 1.0f);
    float p = t * fmaf(t, fmaf(t, fmaf(t, fmaf(t, 1.061405429f, -1.453152027f),
                                        1.421413741f), -0.284496736f), 0.254829592f);
    float e = __expf(-z * z);
    float erfz = fmaf(-p, e, 1.0f);
    float sgn = copysignf(erfz, x);
    return 0.5f * x * (1.0f + sgn);
}

// ---------------------------------------------------------------------------
// Weights f32 -> bf16, 6 segments in one launch. grid (1024, 6).
// ---------------------------------------------------------------------------
struct Cvt6Args {
    const float* src[6];
    ushort_t* dst[6];
    int n[6];
};
__global__ __launch_bounds__(256)
void cvt6(Cvt6Args a)
{
    int seg = blockIdx.y;
    int i = (blockIdx.x * 256 + threadIdx.x) * 4;
    if (i < a.n[seg]) {
        float4 v = *reinterpret_cast<const float4*>(&a.src[seg][i]);
        u32x2 p; p[0] = pack2(v.x, v.y); p[1] = pack2(v.z, v.w);
        *reinterpret_cast<u32x2*>(&a.dst[seg][i]) = p;
    }
}

// ---------------------------------------------------------------------------
// Transpose+convert: f32 [B][C][L] -> bf16 [B][L][C]. grid (L/64, C/64, B)
// ---------------------------------------------------------------------------
__global__ __launch_bounds__(256)
void tcvt(const float* __restrict__ in, ushort_t* __restrict__ outb, int C, int L)
{
    __shared__ float T[64][65];
    int l0 = blockIdx.x * 64, c0 = blockIdx.y * 64, b = blockIdx.z;
    int tid = threadIdx.x;
    int ll = tid & 63, cq = tid >> 6;
    #pragma unroll
    for (int i = 0; i < 16; ++i) {
        int c = cq + i * 4;
        T[c][ll] = in[((size_t)b * C + c0 + c) * L + l0 + ll];
    }
    __syncthreads();
    int cc = tid & 63, lq = tid >> 6;
    #pragma unroll
    for (int i = 0; i < 16; ++i) {
        int l = lq + i * 4;
        outb[((size_t)b * L + l0 + l) * C + c0 + cc] = bfc(T[cc][l]);
    }
}

// ---------------------------------------------------------------------------
// MFMA GEMM (2-phase prefetch, BK=64): Out[b][m][n] = ep(sum_k A[m][k]W[n][k]+bias[n])
// ---------------------------------------------------------------------------
template<int EPI, int STATS>
__global__ __launch_bounds__(256)
void mgemm2(const ushort_t* __restrict__ A, const ushort_t* __restrict__ Wt,
            const float* __restrict__ bias, ushort_t* __restrict__ Out,
            float* __restrict__ part, int M, int N, int K)
{
    __shared__ __align__(16) ushort_t As[2][8192];   // 128 x 64 per buf, swizzled
    __shared__ __align__(16) ushort_t Bs[2][8192];

    int Nt = gridDim.x;
    int flat = blockIdx.y * Nt + blockIdx.x;
    int nwg = Nt * gridDim.y;
    int swz = (flat & 7) * (nwg >> 3) + (flat >> 3);   // nwg % 8 == 0 for all shapes
    int nb = swz % Nt, mb = swz / Nt;
    int b = blockIdx.z;
    int m0 = mb * 128, n0 = nb * 128;

    int tid = threadIdx.x;
    int lane = tid & 63;
    int w = tid >> 6;
    int q16 = lane & 15, g = lane >> 4;
    int wr = w >> 1, wc = w & 1;

    const ushort_t* Ag[4]; const ushort_t* Wg[4];
    #pragma unroll
    for (int i = 0; i < 4; ++i) {
        int gran = w * 256 + i * 64 + lane;      // 16B granule index
        int row = gran >> 3;
        int c8 = (gran & 7) ^ (row & 7);
        Ag[i] = A + ((size_t)b * M + m0 + row) * K + c8 * 8;
        Wg[i] = Wt + ((size_t)(n0 + row)) * K + c8 * 8;
    }

    f32x4 acc[4][4];
    #pragma unroll
    for (int mt = 0; mt < 4; ++mt)
        #pragma unroll
        for (int nt = 0; nt < 4; ++nt) {
            acc[mt][nt][0] = 0.f; acc[mt][nt][1] = 0.f;
            acc[mt][nt][2] = 0.f; acc[mt][nt][3] = 0.f;
        }

    #pragma unroll
    for (int i = 0; i < 4; ++i) {
        gload16(Ag[i], &As[0][w * 2048 + i * 512]);
        gload16(Wg[i], &Bs[0][w * 2048 + i * 512]);
    }

    int NTILES = K >> 6;
    for (int kt = 0; kt < NTILES; ++kt) {
        int cur = kt & 1;
        __syncthreads();
        if (kt + 1 < NTILES) {
            int k0 = (kt + 1) << 6;
            #pragma unroll
            for (int i = 0; i < 4; ++i) {
                gload16(Ag[i] + k0, &As[cur ^ 1][w * 2048 + i * 512]);
                gload16(Wg[i] + k0, &Bs[cur ^ 1][w * 2048 + i * 512]);
            }
        }
        const char* Ab = (const char*)&As[cur][0];
        const char* Bb = (const char*)&Bs[cur][0];
        bf16x8 ka[4][2], kb[4][2];
        #pragma unroll
        for (int mt = 0; mt < 4; ++mt) {
            int r = wr * 64 + mt * 16 + q16;
            int rb = r * 128;
            int sw8 = (r & 7) << 4;
            ka[mt][0] = *reinterpret_cast<const bf16x8*>(Ab + rb + ((g * 16) ^ sw8));
            ka[mt][1] = *reinterpret_cast<const bf16x8*>(Ab + rb + ((64 + g * 16) ^ sw8));
        }
        #pragma unroll
        for (int nt = 0; nt < 4; ++nt) {
            int r = wc * 64 + nt * 16 + q16;
            int rb = r * 128;
            int sw8 = (r & 7) << 4;
            kb[nt][0] = *reinterpret_cast<const bf16x8*>(Bb + rb + ((g * 16) ^ sw8));
            kb[nt][1] = *reinterpret_cast<const bf16x8*>(Bb + rb + ((64 + g * 16) ^ sw8));
        }
        #pragma unroll
        for (int mt = 0; mt < 4; ++mt)
            #pragma unroll
            for (int nt = 0; nt < 4; ++nt) {
                acc[mt][nt] = __builtin_amdgcn_mfma_f32_16x16x32_bf16(kb[nt][0], ka[mt][0], acc[mt][nt], 0, 0, 0);
                acc[mt][nt] = __builtin_amdgcn_mfma_f32_16x16x32_bf16(kb[nt][1], ka[mt][1], acc[mt][nt], 0, 0, 0);
            }
    }

    float4 bv4[4];
    #pragma unroll
    for (int nt = 0; nt < 4; ++nt)
        bv4[nt] = *reinterpret_cast<const float4*>(&bias[n0 + wc * 64 + nt * 16 + g * 4]);

    float s_[4][4], q_[4][4];
    if (STATS) {
        #pragma unroll
        for (int nt = 0; nt < 4; ++nt)
            #pragma unroll
            for (int r = 0; r < 4; ++r) { s_[nt][r] = 0.f; q_[nt][r] = 0.f; }
    }

    #pragma unroll
    for (int mt = 0; mt < 4; ++mt) {
        int m = m0 + wr * 64 + mt * 16 + q16;
        size_t rowoff = ((size_t)b * M + m) * N;
        #pragma unroll
        for (int nt = 0; nt < 4; ++nt) {
            float vv[4];
            #pragma unroll
            for (int r = 0; r < 4; ++r) {
                float val = acc[mt][nt][r] + ((const float*)&bv4[nt])[r];
                if (EPI == 1) val = gelu_fast(val);
                if (STATS) { s_[nt][r] += val; q_[nt][r] = fmaf(val, val, q_[nt][r]); }
                vv[r] = val;
            }
            u32x2 pk; pk[0] = pack2(vv[0], vv[1]); pk[1] = pack2(vv[2], vv[3]);
            *reinterpret_cast<u32x2*>(&Out[rowoff + n0 + wc * 64 + nt * 16 + g * 4]) = pk;
        }
    }

    if (STATS) {
        __syncthreads();
        float* SS = (float*)&As[0][0];   // [128][33]
        float* SQ = (float*)&Bs[0][0];
        #pragma unroll
        for (int nt = 0; nt < 4; ++nt)
            #pragma unroll
            for (int r = 0; r < 4; ++r) {
                int nl = wc * 64 + nt * 16 + g * 4 + r;
                SS[nl * 33 + wr * 16 + q16] = s_[nt][r];
                SQ[nl * 33 + wr * 16 + q16] = q_[nt][r];
            }
        __syncthreads();
        if (tid < 128) {
            float ts = 0.f, tq = 0.f;
            #pragma unroll 8
            for (int j = 0; j < 32; ++j) { ts += SS[tid * 33 + j]; tq += SQ[tid * 33 + j]; }
            size_t po = (((size_t)b * (M >> 7) + mb) * N + n0 + tid) * 2;
            part[po] = ts; part[po + 1] = tq;
        }
    }
}

// ---------------------------------------------------------------------------
// Column-norm apply (vectorized, bf16 in/out, C=512). grid (L/16, 1, B).
// out = (in-mean)*rstd*oscale (+ res). In-place safe.
// ---------------------------------------------------------------------------
template<int RES>
__global__ __launch_bounds__(256)
void cn_apply_v(const ushort_t* __restrict__ in, const float* __restrict__ part,
                const ushort_t* __restrict__ res, ushort_t* __restrict__ out,
                int L, int SPLITM, float oscale)
{
    __shared__ float SM[CDIM], SR[CDIM];
    int b = blockIdx.z;
    int tid = threadIdx.x;
    for (int c = tid; c < CDIM; c += 256) {
        float fs = 0.f, fq = 0.f;
        for (int sp = 0; sp < SPLITM; ++sp) {
            size_t po = (((size_t)b * SPLITM + sp) * CDIM + c) * 2;
            fs += part[po]; fq += part[po + 1];
        }
        float mean = fs / (float)L;
        float var = fq / (float)L - mean * mean;
        SM[c] = mean; SR[c] = rsqrtf(var + 1e-5f) * oscale;
    }
    __syncthreads();
    int c0 = (tid & 63) * 8;
    int l0 = blockIdx.x * 16 + (tid >> 6) * 4;
    float mm[8], rr[8];
    #pragma unroll
    for (int j = 0; j < 8; ++j) { mm[j] = SM[c0 + j]; rr[j] = SR[c0 + j]; }
    #pragma unroll
    for (int i = 0; i < 4; ++i) {
        int l = l0 + i;
        size_t off = ((size_t)b * L + l) * CDIM + c0;
        u16x8 v = *reinterpret_cast<const u16x8*>(in + off);
        u16x8 rv;
        if (RES) rv = *reinterpret_cast<const u16x8*>(res + off);
        u16x8 o;
        #pragma unroll
        for (int j = 0; j < 8; ++j) {
            float y = (bf2f((ushort_t)v[j]) - mm[j]) * rr[j];
            if (RES) y += bf2f((ushort_t)rv[j]);
            o[j] = bfc(y);
        }
        *reinterpret_cast<u16x8*>(out + off) = o;
    }
}

// ---------------------------------------------------------------------------
// Final: out[B][C][L] f32 = norm(in)[l][c] + res[l][c], transposed write.
// ---------------------------------------------------------------------------
__global__ __launch_bounds__(256)
void cn_apply_t(const ushort_t* __restrict__ in, const float* __restrict__ part,
                const ushort_t* __restrict__ res, float* __restrict__ outf,
                int L, int SPLITM)
{
    __shared__ float SM[64], SR[64];
    __shared__ float T[64][65];
    int b = blockIdx.z;
    int c0 = blockIdx.x * 64;
    int l0 = blockIdx.y * 64;
    int tid = threadIdx.x;
    if (tid < 64) {
        int c = c0 + tid;
        float fs = 0.f, fq = 0.f;
        for (int sp = 0; sp < SPLITM; ++sp) {
            size_t po = (((size_t)b * SPLITM + sp) * CDIM + c) * 2;
            fs += part[po]; fq += part[po + 1];
        }
        float mean = fs / (float)L;
        float var = fq / (float)L - mean * mean;
        SM[tid] = mean; SR[tid] = rsqrtf(var + 1e-5f);
    }
    __syncthreads();
    int cc = tid & 63;
    int lq = tid >> 6;
    float mean = SM[cc], rstd = SR[cc];
    #pragma unroll
    for (int i = 0; i < 16; ++i) {
        int l = l0 + lq + i * 4;
        size_t idx = ((size_t)b * L + l) * CDIM + c0 + cc;
        T[lq + i * 4][cc] = (bf2f(in[idx]) - mean) * rstd + bf2f(res[idx]);
    }
    __syncthreads();
    int ll = tid & 63;
    int cr = tid >> 6;
    #pragma unroll
    for (int i = 0; i < 16; ++i) {
        int c = cr + i * 4;
        outf[((size_t)b * CDIM + c0 + c) * L + l0 + ll] = T[ll][c];
    }
}

// ---------------------------------------------------------------------------
// MFMA 32x32 windowed cross attention. One block (512 thr / 8 waves) per
// (n, h, b). qT (pre-scaled by 0.125*log2e) / kT / vT: bf16 [B][L][CDIM].
// win out: (B,NH,NWIN,WINQ,HD) bf16.
// Per wave: 32 q-rows. S^T = K.Q (lane owns col q = lane&31), softmax in
// exp2-space with defer-max; P^T B-frags built via pack2 + shfl_xor(32);
// O^T = V^T.P^T accumulated in 2 f32x16.
// ---------------------------------------------------------------------------
__global__ __launch_bounds__(512, 2)
void attn_win_mfma32(const ushort_t* __restrict__ qT, const ushort_t* __restrict__ kT,
                     const ushort_t* __restrict__ vT, ushort_t* __restrict__ win)
{
    __shared__ __align__(16) char KB[65536];   // K: [512 kpos][64 d], chunk ^= (kpos&7)<<4
    __shared__ __align__(16) char VB[65536];   // V^T: [64 d][512 kpos], off ^= Sv(d)

    int n = blockIdx.x, hh = blockIdx.y, b = blockIdx.z;
    int s = n * WSTRIDE;
    int es = 2 * s;
    bool tail = (n == NWIN - 1);
    int ncc = tail ? 2 : 8;

    int tid = threadIdx.x;
    int lane = tid & 63;
    int w = tid >> 6;
    int l31 = lane & 31;
    int hf = lane >> 5;

    // ---- stage K via global_load_lds (pre-swizzled per-lane source) ----
    {
        const ushort_t* kbase = kT + (size_t)b * LEE * CDIM + hh * HD;
        #pragma unroll
        for (int iss = 0; iss < 8; ++iss) {
            int o = w * 8192 + iss * 1024 + lane * 16;
            int kpos = o >> 7;
            int slot = (o >> 4) & 7;
            int c8 = slot ^ (kpos & 7);
            int srow = min(es + kpos, LEE - 1);
            gload16(kbase + (size_t)srow * CDIM + c8 * 8, KB + w * 8192 + iss * 1024);
        }
    }
    // ---- stage V^T: [d][kpos], swizzle Sv(d) = ((d&7)<<4)^((d&24)<<2) ----
    {
        const ushort_t* vbase = vT + (size_t)b * LEE * CDIM + hh * HD;
        #pragma unroll
        for (int it = 0; it < 4; ++it) {
            int idx = tid + it * 512;
            int c8 = idx & 7;
            int kp = idx >> 3;            // kpos pair 0..255
            int r0 = min(es + 2 * kp, LEE - 1);
            int r1 = min(es + 2 * kp + 1, LEE - 1);
            u16x8 wa = *reinterpret_cast<const u16x8*>(vbase + (size_t)r0 * CDIM + c8 * 8);
            u16x8 wb = *reinterpret_cast<const u16x8*>(vbase + (size_t)r1 * CDIM + c8 * 8);
            #pragma unroll
            for (int j = 0; j < 8; ++j) {
                int d = c8 * 8 + j;
                uint32_t dw = (uint32_t)wa[j] | ((uint32_t)wb[j] << 16);
                int sv = ((d & 7) << 4) ^ ((d & 24) << 2);
                int byte = d * 1024 + ((kp * 4) ^ sv);
                *reinterpret_cast<uint32_t*>(&VB[byte]) = dw;
            }
        }
    }
    __syncthreads();
    if (tail && w >= 2) return;

    // ---- Q fragments (B-operand: col q = lane&31, rows d = hf*8 + j) ----
    int qrow_g = s + w * 32 + l31;
    const ushort_t* qp = qT + ((size_t)b * LDD + qrow_g) * CDIM + hh * HD;
    bf16x8 bq[4];
    #pragma unroll
    for (int kd = 0; kd < 4; ++kd)
        bq[kd] = *reinterpret_cast<const bf16x8*>(qp + kd * 16 + hf * 8);

    f32x16 acc0, acc1;
    #pragma unroll
    for (int e = 0; e < 16; ++e) { acc0[e] = 0.f; acc1[e] = 0.f; }
    float m = -3e38f, ssum = 0.f;

    int swk = (lane & 7) << 4;
    int sv  = ((lane & 7) << 4) ^ ((l31 & 24) << 2);
    const char* VB0 = VB + (size_t)l31 * 1024;
    const char* VB1 = VB0 + 32 * 1024;

    for (int cc = 0; cc < ncc; ++cc) {
        // ---- S^T: A = K (rows kpos, cols d), B = Q ----
        f32x16 st0, st1;
        #pragma unroll
        for (int e = 0; e < 16; ++e) { st0[e] = 0.f; st1[e] = 0.f; }
        const char* KA0 = KB + (size_t)(cc * 64 + l31) * 128;
        const char* KA1 = KA0 + 32 * 128;
        #pragma unroll
        for (int kd = 0; kd < 4; ++kd) {
            int co = (kd * 32 + hf * 16) ^ swk;
            bf16x8 ka0 = *reinterpret_cast<const bf16x8*>(KA0 + co);
            bf16x8 ka1 = *reinterpret_cast<const bf16x8*>(KA1 + co);
            st0 = __builtin_amdgcn_mfma_f32_32x32x16_bf16(ka0, bq[kd], st0, 0, 0, 0);
            st1 = __builtin_amdgcn_mfma_f32_32x32x16_bf16(ka1, bq[kd], st1, 0, 0, 0);
        }
        // ---- online softmax (exp2 space), defer-max THR=11.5 ----
        float pmax = st0[0];
        #pragma unroll
        for (int e = 1; e < 16; ++e) pmax = fmaxf(pmax, st0[e]);
        #pragma unroll
        for (int e = 0; e < 16; ++e) pmax = fmaxf(pmax, st1[e]);
        pmax = fmaxf(pmax, __shfl_xor(pmax, 32));
        if (!__all(pmax <= m + 11.5f)) {
            float mnew = fmaxf(m, pmax);
            float corr = exp2f(m - mnew);
            m = mnew;
            ssum *= corr;
            #pragma unroll
            for (int e = 0; e < 16; ++e) { acc0[e] *= corr; acc1[e] *= corr; }
        }
        uint32_t pk0[8], pk1[8];
        float ls = 0.f;
        #pragma unroll
        for (int p = 0; p < 8; ++p) {
            float a = exp2f(st0[2 * p] - m), bb = exp2f(st0[2 * p + 1] - m);
            float c = exp2f(st1[2 * p] - m), dd = exp2f(st1[2 * p + 1] - m);
            ls += (a + bb) + (c + dd);
            pk0[p] = pack2(a, bb);
            pk1[p] = pack2(c, dd);
        }
        ssum += ls;
        // ---- PV: O^T += V^T . P^T ----
        #pragma unroll
        for (int kc = 0; kc < 4; ++kc) {
            const int sub = kc & 1;
            uint32_t pA0, pA1, pA2, pA3;
            if ((kc >> 1) == 0) { pA0 = pk0[4*sub]; pA1 = pk0[4*sub+1]; pA2 = pk0[4*sub+2]; pA3 = pk0[4*sub+3]; }
            else                { pA0 = pk1[4*sub]; pA1 = pk1[4*sub+1]; pA2 = pk1[4*sub+2]; pA3 = pk1[4*sub+3]; }
            uint32_t s0 = hf ? pA0 : pA2;
            uint32_t s1 = hf ? pA1 : pA3;
            uint32_t r0 = (uint32_t)__shfl_xor((int)s0, 32);
            uint32_t r1 = (uint32_t)__shfl_xor((int)s1, 32);
            u32x4 bt;
            bt[0] = hf ? r0 : pA0;
            bt[1] = hf ? r1 : pA1;
            bt[2] = hf ? pA2 : r0;
            bt[3] = hf ? pA3 : r1;
            bf16x8 pbf = __builtin_bit_cast(bf16x8, bt);
            int kb2 = cc * 128 + kc * 32 + hf * 16;
            bf16x8 va0 = *reinterpret_cast<const bf16x8*>(VB0 + (kb2 ^ sv));
            bf16x8 va1 = *reinterpret_cast<const bf16x8*>(VB1 + (kb2 ^ sv));
            acc0 = __builtin_amdgcn_mfma_f32_32x32x16_bf16(va0, pbf, acc0, 0, 0, 0);
            acc1 = __builtin_amdgcn_mfma_f32_32x32x16_bf16(va1, pbf, acc1, 0, 0, 0);
        }
    }
    // ---- epilogue: rows d = 8p + 4hf + e, col q = l31 ----
    float stot = ssum + __shfl_xor(ssum, 32);
    float rs = 1.f / stot;
    size_t wbase = (((size_t)(b * NHEAD + hh) * NWIN + n) * WINQ + (size_t)(w * 32 + l31)) * HD;
    #pragma unroll
    for (int p = 0; p < 4; ++p) {
        u32x2 o0, o1;
        o0[0] = pack2(acc0[4*p] * rs, acc0[4*p+1] * rs);
        o0[1] = pack2(acc0[4*p+2] * rs, acc0[4*p+3] * rs);
        o1[0] = pack2(acc1[4*p] * rs, acc1[4*p+1] * rs);
        o1[1] = pack2(acc1[4*p+2] * rs, acc1[4*p+3] * rs);
        *reinterpret_cast<u32x2*>(&win[wbase + p * 8 + hf * 4]) = o0;
        *reinterpret_cast<u32x2*>(&win[wbase + 32 + p * 8 + hf * 4]) = o1;
    }
}

// ---------------------------------------------------------------------------
// Overlap-add + count-normalize (bf16 win) -> bf16 [B][L][CDIM].
// grid (LDD/64, NHEAD, NB)
// ---------------------------------------------------------------------------
__global__ __launch_bounds__(256)
void attn_finalize(const ushort_t* __restrict__ win, ushort_t* __restrict__ outT)
{
    int l0 = blockIdx.x * 64;
    int hh = blockIdx.y, b = blockIdx.z;
    int tid = threadIdx.x;
    int d2 = tid & 31;            // d-pair index
    int lq = tid >> 5;            // 0..7
    #pragma unroll
    for (int i = 0; i < 8; ++i) {
        int ll = lq + i * 8;
        int l = l0 + ll;
        int n1 = min(NWIN - 1, l / WSTRIDE);
        int n0 = (l >= 64) ? ((l - 64) / WSTRIDE) : 0;
        float a0 = 0.f, a1 = 0.f;
        for (int nn = n0; nn <= n1; ++nn) {
            int qrow = l - nn * WSTRIDE;
            uint32_t v = *reinterpret_cast<const uint32_t*>(
                &win[(((size_t)(b * NHEAD + hh) * NWIN + nn) * WINQ + qrow) * HD + d2 * 2]);
            a0 += bf2f((ushort_t)(v & 0xffffu));
            a1 += bf2f((ushort_t)(v >> 16));
        }
        float inv = 1.f / (float)(n1 - n0 + 1);
        uint32_t o = pack2(a0 * inv, a1 * inv);
        *reinterpret_cast<uint32_t*>(
            &outT[((size_t)b * LDD + l) * CDIM + hh * HD + d2 * 2]) = o;
    }
}

// ---------------------------------------------------------------------------
extern "C" void kernel_launch(void* const* d_in, const int* in_sizes, int n_in,
                              void* d_out, int out_size, void* d_ws, size_t ws_size,
                              hipStream_t stream)
{
    const float* x_dec = (const float*)d_in[0];
    const float* x_enc = (const float*)d_in[1];
    const float* wq = (const float*)d_in[2];
    const float* bq = (const float*)d_in[3];
    const float* wk = (const float*)d_in[4];
    const float* bk = (const float*)d_in[5];
    const float* wv = (const float*)d_in[6];
    const float* bv = (const float*)d_in[7];
    const float* wo = (const float*)d_in[8];
    const float* bo = (const float*)d_in[9];
    const float* w1 = (const float*)d_in[10];
    const float* b1 = (const float*)d_in[11];
    const float* w2 = (const float*)d_in[12];
    const float* b2 = (const float*)d_in[13];
    float* out = (float*)d_out;

    // ---- workspace carve (bytes) ----
    char* base = (char*)d_ws;
    ushort_t* wqb = (ushort_t*)(base);
    ushort_t* wkb = (ushort_t*)(base + 524288);
    ushort_t* wvb = (ushort_t*)(base + 786432);
    ushort_t* wob = (ushort_t*)(base + 1048576);
    ushort_t* w1b = (ushort_t*)(base + 1572864);
    ushort_t* w2b = (ushort_t*)(base + 3670016);
    ushort_t* x_decT_b = (ushort_t*)(base + 5767168);    // 16.8 MB
    ushort_t* q_pre    = (ushort_t*)(base + 22544384);   // 16.8 MB -> xo_pre/xres
    ushort_t* k_pre    = (ushort_t*)(base + 39321600);   // 33.5 MB -> hT (with v)
    ushort_t* v_pre    = (ushort_t*)(base + 72876032);   // 33.5 MB
    ushort_t* x_encT_b = (ushort_t*)(base + 106430464);  // 16.8 MB -> attn_outT
    ushort_t* winb     = (ushort_t*)(base + 123207680);  // 23.1 MB bf16 -> y_pre
    float*    part     = (float*)(base + 169345024);     // 1 MB
    ushort_t* attn_outT = x_encT_b;
    ushort_t* xo_pre   = q_pre;
    ushort_t* hT       = k_pre;
    ushort_t* y_pre    = winb;

    dim3 blk(256);

    // 0. weights -> bf16
    Cvt6Args ca;
    ca.src[0] = wq; ca.src[1] = wk; ca.src[2] = wv;
    ca.src[3] = wo; ca.src[4] = w1; ca.src[5] = w2;
    ca.dst[0] = wqb; ca.dst[1] = wkb; ca.dst[2] = wvb;
    ca.dst[3] = wob; ca.dst[4] = w1b; ca.dst[5] = w2b;
    ca.n[0] = 262144; ca.n[1] = 131072; ca.n[2] = 131072;
    ca.n[3] = 262144; ca.n[4] = 1048576; ca.n[5] = 1048576;
    cvt6<<<dim3(1024, 6), blk, 0, stream>>>(ca);

    // 1. transpose inputs to [B][L][C] bf16
    tcvt<<<dim3(LDD / 64, CDIM / 64, NB), blk, 0, stream>>>(x_dec, x_decT_b, CDIM, LDD);
    tcvt<<<dim3(LEE / 64, CENC / 64, NB), blk, 0, stream>>>(x_enc, x_encT_b, CENC, LEE);

    const float QSCALE = 0.125f * 1.4426950408889634f;   // fold 1/sqrt(hd) and log2(e)

    // 2. q = IN(x_decT @ wq^T + bq) * QSCALE
    mgemm2<0,1><<<dim3(CDIM / 128, LDD / 128, NB), blk, 0, stream>>>(x_decT_b, wqb, bq, q_pre, part, LDD, CDIM, CDIM);
    cn_apply_v<0><<<dim3(LDD / 16, 1, NB), blk, 0, stream>>>(q_pre, part, nullptr, q_pre, LDD, LDD / 128, QSCALE);

    // 3. k
    mgemm2<0,1><<<dim3(CDIM / 128, LEE / 128, NB), blk, 0, stream>>>(x_encT_b, wkb, bk, k_pre, part, LEE, CDIM, CENC);
    cn_apply_v<0><<<dim3(LEE / 16, 1, NB), blk, 0, stream>>>(k_pre, part, nullptr, k_pre, LEE, LEE / 128, 1.0f);

    // 4. v
    mgemm2<0,1><<<dim3(CDIM / 128, LEE / 128, NB), blk, 0, stream>>>(x_encT_b, wvb, bv, v_pre, part, LEE, CDIM, CENC);
    cn_apply_v<0><<<dim3(LEE / 16, 1, NB), blk, 0, stream>>>(v_pre, part, nullptr, v_pre, LEE, LEE / 128, 1.0f);

    // 5. windowed attention + overlap-add
    attn_win_mfma32<<<dim3(NWIN, NHEAD, NB), dim3(512), 0, stream>>>(q_pre, k_pre, v_pre, winb);
    attn_finalize<<<dim3(LDD / 64, NHEAD, NB), blk, 0, stream>>>(winb, attn_outT);

    // 6. xres = IN(attn_outT @ wo^T + bo) + x_decT
    mgemm2<0,1><<<dim3(CDIM / 128, LDD / 128, NB), blk, 0, stream>>>(attn_outT, wob, bo, xo_pre, part, LDD, CDIM, CDIM);
    cn_apply_v<1><<<dim3(LDD / 16, 1, NB), blk, 0, stream>>>(xo_pre, part, x_decT_b, xo_pre, LDD, LDD / 128, 1.0f);

    // 7. h = gelu(xres @ w1^T + b1)
    mgemm2<1,0><<<dim3(HDIM / 128, LDD / 128, NB), blk, 0, stream>>>(xo_pre, w1b, b1, hT, nullptr, LDD, HDIM, CDIM);

    // 8. y = IN(h @ w2^T + b2) + xres -> f32 [B][C][L]
    mgemm2<0,1><<<dim3(CDIM / 128, LDD / 128, NB), blk, 0, stream>>>(hT, w2b, b2, y_pre, part, LDD, CDIM, HDIM);
    cn_apply_t<<<dim3(CDIM / 64, LDD / 64, NB), blk, 0, stream>>>(y_pre, part, xo_pre, out, LDD, LDD / 128);

    (void)in_sizes; (void)n_in; (void)out_size; (void)ws_size;
}

// Round 6
// 354.140 us; speedup vs baseline: 8.7671x; 1.2400x over previous
//
#include <hip/hip_runtime.h>
#include <hip/hip_bf16.h>
#include <math.h>
#include <stdint.h>

#define LDD 4096
#define LEE 8192
#define CDIM 512
#define CENC 256
#define HDIM 2048
#define NB 4
#define NHEAD 8
#define HD 64
#define NWIN 22
#define WINQ 256
#define WSTRIDE 192

typedef __attribute__((ext_vector_type(8))) short bf16x8;
typedef __attribute__((ext_vector_type(8))) unsigned short u16x8;
typedef __attribute__((ext_vector_type(4))) float f32x4;
typedef __attribute__((ext_vector_type(16))) float f32x16;
typedef __attribute__((ext_vector_type(2))) unsigned int u32x2;
typedef __attribute__((ext_vector_type(4))) unsigned int u32x4;
typedef unsigned short ushort_t;

__device__ __forceinline__ uint32_t pack2(float lo, float hi) {
    return ((__float_as_uint(hi) + 0x8000u) & 0xffff0000u) |
           ((__float_as_uint(lo) + 0x8000u) >> 16);
}
__device__ __forceinline__ ushort_t bfc(float x) {
    return (ushort_t)((__float_as_uint(x) + 0x8000u) >> 16);
}
__device__ __forceinline__ float bf2f(ushort_t u) {
    return __uint_as_float(((uint32_t)u) << 16);
}
__device__ __forceinline__ void gload16(const void* g, void* l) {
    __builtin_amdgcn_global_load_lds(
        (const __attribute__((address_space(1))) void*)g,
        (__attribute__((address_space(3))) void*)l, 16, 0, 0);
}
// fast erf-based gelu (A&S 7.1.26, |eps| <= 1.5e-7)
__device__ __forceinline__ float gelu_fast(float x) {
    float z = fabsf(x) * 0.70710678f;
    float t = 1.0f / fmaf(0.3275911f, z, 1.0f);
    float p = t * fmaf(t, fmaf(t, fmaf(t, fmaf(t, 1.061405429f, -1.453152027f),
                                        1.421413741f), -0.284496736f), 0.254829592f);
    float e = __expf(-z * z);
    float erfz = fmaf(-p, e, 1.0f);
    float sgn = copysignf(erfz, x);
    return 0.5f * x * (1.0f + sgn);
}

// ---------------------------------------------------------------------------
// Weights f32 -> bf16, 6 segments in one launch. grid (1024, 6).
// ---------------------------------------------------------------------------
struct Cvt6Args {
    const float* src[6];
    ushort_t* dst[6];
    int n[6];
};
__global__ __launch_bounds__(256)
void cvt6(Cvt6Args a)
{
    int seg = blockIdx.y;
    int i = (blockIdx.x * 256 + threadIdx.x) * 4;
    if (i < a.n[seg]) {
        float4 v = *reinterpret_cast<const float4*>(&a.src[seg][i]);
        u32x2 p; p[0] = pack2(v.x, v.y); p[1] = pack2(v.z, v.w);
        *reinterpret_cast<u32x2*>(&a.dst[seg][i]) = p;
    }
}

// ---------------------------------------------------------------------------
// Transpose+convert: f32 [B][C][L] -> bf16 [B][L][C]. grid (L/64, C/64, B)
// ---------------------------------------------------------------------------
__global__ __launch_bounds__(256)
void tcvt(const float* __restrict__ in, ushort_t* __restrict__ outb, int C, int L)
{
    __shared__ float T[64][65];
    int l0 = blockIdx.x * 64, c0 = blockIdx.y * 64, b = blockIdx.z;
    int tid = threadIdx.x;
    int ll = tid & 63, cq = tid >> 6;
    #pragma unroll
    for (int i = 0; i < 16; ++i) {
        int c = cq + i * 4;
        T[c][ll] = in[((size_t)b * C + c0 + c) * L + l0 + ll];
    }
    __syncthreads();
    int cc = tid & 63, lq = tid >> 6;
    #pragma unroll
    for (int i = 0; i < 16; ++i) {
        int l = lq + i * 4;
        outb[((size_t)b * L + l0 + l) * C + c0 + cc] = bfc(T[cc][l]);
    }
}

// ---------------------------------------------------------------------------
// MFMA GEMM (2-phase prefetch, BK=64): Out[b][m][n] = ep(sum_k A[m][k]W[n][k]+bias[n])
// ---------------------------------------------------------------------------
template<int EPI, int STATS>
__global__ __launch_bounds__(256)
void mgemm2(const ushort_t* __restrict__ A, const ushort_t* __restrict__ Wt,
            const float* __restrict__ bias, ushort_t* __restrict__ Out,
            float* __restrict__ part, int M, int N, int K)
{
    __shared__ __align__(16) ushort_t As[2][8192];   // 128 x 64 per buf, swizzled
    __shared__ __align__(16) ushort_t Bs[2][8192];

    int Nt = gridDim.x;
    int flat = blockIdx.y * Nt + blockIdx.x;
    int nwg = Nt * gridDim.y;
    int swz = (flat & 7) * (nwg >> 3) + (flat >> 3);   // nwg % 8 == 0 for all shapes
    int nb = swz % Nt, mb = swz / Nt;
    int b = blockIdx.z;
    int m0 = mb * 128, n0 = nb * 128;

    int tid = threadIdx.x;
    int lane = tid & 63;
    int w = tid >> 6;
    int q16 = lane & 15, g = lane >> 4;
    int wr = w >> 1, wc = w & 1;

    const ushort_t* Ag[4]; const ushort_t* Wg[4];
    #pragma unroll
    for (int i = 0; i < 4; ++i) {
        int gran = w * 256 + i * 64 + lane;      // 16B granule index
        int row = gran >> 3;
        int c8 = (gran & 7) ^ (row & 7);
        Ag[i] = A + ((size_t)b * M + m0 + row) * K + c8 * 8;
        Wg[i] = Wt + ((size_t)(n0 + row)) * K + c8 * 8;
    }

    f32x4 acc[4][4];
    #pragma unroll
    for (int mt = 0; mt < 4; ++mt)
        #pragma unroll
        for (int nt = 0; nt < 4; ++nt) {
            acc[mt][nt][0] = 0.f; acc[mt][nt][1] = 0.f;
            acc[mt][nt][2] = 0.f; acc[mt][nt][3] = 0.f;
        }

    #pragma unroll
    for (int i = 0; i < 4; ++i) {
        gload16(Ag[i], &As[0][w * 2048 + i * 512]);
        gload16(Wg[i], &Bs[0][w * 2048 + i * 512]);
    }

    int NTILES = K >> 6;
    for (int kt = 0; kt < NTILES; ++kt) {
        int cur = kt & 1;
        __syncthreads();
        if (kt + 1 < NTILES) {
            int k0 = (kt + 1) << 6;
            #pragma unroll
            for (int i = 0; i < 4; ++i) {
                gload16(Ag[i] + k0, &As[cur ^ 1][w * 2048 + i * 512]);
                gload16(Wg[i] + k0, &Bs[cur ^ 1][w * 2048 + i * 512]);
            }
        }
        const char* Ab = (const char*)&As[cur][0];
        const char* Bb = (const char*)&Bs[cur][0];
        bf16x8 ka[4][2], kb[4][2];
        #pragma unroll
        for (int mt = 0; mt < 4; ++mt) {
            int r = wr * 64 + mt * 16 + q16;
            int rb = r * 128;
            int sw8 = (r & 7) << 4;
            ka[mt][0] = *reinterpret_cast<const bf16x8*>(Ab + rb + ((g * 16) ^ sw8));
            ka[mt][1] = *reinterpret_cast<const bf16x8*>(Ab + rb + ((64 + g * 16) ^ sw8));
        }
        #pragma unroll
        for (int nt = 0; nt < 4; ++nt) {
            int r = wc * 64 + nt * 16 + q16;
            int rb = r * 128;
            int sw8 = (r & 7) << 4;
            kb[nt][0] = *reinterpret_cast<const bf16x8*>(Bb + rb + ((g * 16) ^ sw8));
            kb[nt][1] = *reinterpret_cast<const bf16x8*>(Bb + rb + ((64 + g * 16) ^ sw8));
        }
        #pragma unroll
        for (int mt = 0; mt < 4; ++mt)
            #pragma unroll
            for (int nt = 0; nt < 4; ++nt) {
                acc[mt][nt] = __builtin_amdgcn_mfma_f32_16x16x32_bf16(kb[nt][0], ka[mt][0], acc[mt][nt], 0, 0, 0);
                acc[mt][nt] = __builtin_amdgcn_mfma_f32_16x16x32_bf16(kb[nt][1], ka[mt][1], acc[mt][nt], 0, 0, 0);
            }
    }

    float4 bv4[4];
    #pragma unroll
    for (int nt = 0; nt < 4; ++nt)
        bv4[nt] = *reinterpret_cast<const float4*>(&bias[n0 + wc * 64 + nt * 16 + g * 4]);

    float s_[4][4], q_[4][4];
    if (STATS) {
        #pragma unroll
        for (int nt = 0; nt < 4; ++nt)
            #pragma unroll
            for (int r = 0; r < 4; ++r) { s_[nt][r] = 0.f; q_[nt][r] = 0.f; }
    }

    #pragma unroll
    for (int mt = 0; mt < 4; ++mt) {
        int m = m0 + wr * 64 + mt * 16 + q16;
        size_t rowoff = ((size_t)b * M + m) * N;
        #pragma unroll
        for (int nt = 0; nt < 4; ++nt) {
            float vv[4];
            #pragma unroll
            for (int r = 0; r < 4; ++r) {
                float val = acc[mt][nt][r] + ((const float*)&bv4[nt])[r];
                if (EPI == 1) val = gelu_fast(val);
                if (STATS) { s_[nt][r] += val; q_[nt][r] = fmaf(val, val, q_[nt][r]); }
                vv[r] = val;
            }
            u32x2 pk; pk[0] = pack2(vv[0], vv[1]); pk[1] = pack2(vv[2], vv[3]);
            *reinterpret_cast<u32x2*>(&Out[rowoff + n0 + wc * 64 + nt * 16 + g * 4]) = pk;
        }
    }

    if (STATS) {
        __syncthreads();
        float* SS = (float*)&As[0][0];   // [128][33]
        float* SQ = (float*)&Bs[0][0];
        #pragma unroll
        for (int nt = 0; nt < 4; ++nt)
            #pragma unroll
            for (int r = 0; r < 4; ++r) {
                int nl = wc * 64 + nt * 16 + g * 4 + r;
                SS[nl * 33 + wr * 16 + q16] = s_[nt][r];
                SQ[nl * 33 + wr * 16 + q16] = q_[nt][r];
            }
        __syncthreads();
        if (tid < 128) {
            float ts = 0.f, tq = 0.f;
            #pragma unroll 8
            for (int j = 0; j < 32; ++j) { ts += SS[tid * 33 + j]; tq += SQ[tid * 33 + j]; }
            size_t po = (((size_t)b * (M >> 7) + mb) * N + n0 + tid) * 2;
            part[po] = ts; part[po + 1] = tq;
        }
    }
}

// ---------------------------------------------------------------------------
// Finish per-channel stats for k and v: part[b][64][512][2] -> mean/rstd.
// grid (8) x 256 thr: one thread per (b, c).
// ---------------------------------------------------------------------------
__global__ __launch_bounds__(256)
void stats_finish(const float* __restrict__ pk, const float* __restrict__ pv,
                  float* __restrict__ km, float* __restrict__ kr,
                  float* __restrict__ vm, float* __restrict__ vr)
{
    int id = blockIdx.x * 256 + threadIdx.x;   // 0..2047
    int b = id >> 9, c = id & 511;
    float sk = 0.f, qk = 0.f, sv = 0.f, qv = 0.f;
    for (int sp = 0; sp < 64; ++sp) {
        size_t po = (((size_t)(b * 64 + sp)) * CDIM + c) * 2;
        sk += pk[po]; qk += pk[po + 1];
        sv += pv[po]; qv += pv[po + 1];
    }
    float mk = sk / (float)LEE, mv = sv / (float)LEE;
    km[id] = mk;
    kr[id] = rsqrtf(qk / (float)LEE - mk * mk + 1e-5f);
    vm[id] = mv;
    vr[id] = rsqrtf(qv / (float)LEE - mv * mv + 1e-5f);
}

// ---------------------------------------------------------------------------
// Column-norm apply (vectorized, bf16 in/out, C=512). grid (L/16, 1, B).
// out = (in-mean)*rstd*oscale*chscale[c] (+ res). In-place safe.
// ---------------------------------------------------------------------------
template<int RES>
__global__ __launch_bounds__(256)
void cn_apply_v(const ushort_t* __restrict__ in, const float* __restrict__ part,
                const ushort_t* __restrict__ res, ushort_t* __restrict__ out,
                const float* __restrict__ chscale,
                int L, int SPLITM, float oscale)
{
    __shared__ float SM[CDIM], SR[CDIM];
    int b = blockIdx.z;
    int tid = threadIdx.x;
    for (int c = tid; c < CDIM; c += 256) {
        float fs = 0.f, fq = 0.f;
        for (int sp = 0; sp < SPLITM; ++sp) {
            size_t po = (((size_t)b * SPLITM + sp) * CDIM + c) * 2;
            fs += part[po]; fq += part[po + 1];
        }
        float mean = fs / (float)L;
        float var = fq / (float)L - mean * mean;
        float sc = oscale;
        if (chscale) sc *= chscale[b * CDIM + c];
        SM[c] = mean; SR[c] = rsqrtf(var + 1e-5f) * sc;
    }
    __syncthreads();
    int c0 = (tid & 63) * 8;
    int l0 = blockIdx.x * 16 + (tid >> 6) * 4;
    float mm[8], rr[8];
    #pragma unroll
    for (int j = 0; j < 8; ++j) { mm[j] = SM[c0 + j]; rr[j] = SR[c0 + j]; }
    #pragma unroll
    for (int i = 0; i < 4; ++i) {
        int l = l0 + i;
        size_t off = ((size_t)b * L + l) * CDIM + c0;
        u16x8 v = *reinterpret_cast<const u16x8*>(in + off);
        u16x8 rv;
        if (RES) rv = *reinterpret_cast<const u16x8*>(res + off);
        u16x8 o;
        #pragma unroll
        for (int j = 0; j < 8; ++j) {
            float y = (bf2f((ushort_t)v[j]) - mm[j]) * rr[j];
            if (RES) y += bf2f((ushort_t)rv[j]);
            o[j] = bfc(y);
        }
        *reinterpret_cast<u16x8*>(out + off) = o;
    }
}

// ---------------------------------------------------------------------------
// Final: out[B][C][L] f32 = norm(in)[l][c] + res[l][c], transposed write.
// ---------------------------------------------------------------------------
__global__ __launch_bounds__(256)
void cn_apply_t(const ushort_t* __restrict__ in, const float* __restrict__ part,
                const ushort_t* __restrict__ res, float* __restrict__ outf,
                int L, int SPLITM)
{
    __shared__ float SM[64], SR[64];
    __shared__ float T[64][65];
    int b = blockIdx.z;
    int c0 = blockIdx.x * 64;
    int l0 = blockIdx.y * 64;
    int tid = threadIdx.x;
    if (tid < 64) {
        int c = c0 + tid;
        float fs = 0.f, fq = 0.f;
        for (int sp = 0; sp < SPLITM; ++sp) {
            size_t po = (((size_t)b * SPLITM + sp) * CDIM + c) * 2;
            fs += part[po]; fq += part[po + 1];
        }
        float mean = fs / (float)L;
        float var = fq / (float)L - mean * mean;
        SM[tid] = mean; SR[tid] = rsqrtf(var + 1e-5f);
    }
    __syncthreads();
    int cc = tid & 63;
    int lq = tid >> 6;
    float mean = SM[cc], rstd = SR[cc];
    #pragma unroll
    for (int i = 0; i < 16; ++i) {
        int l = l0 + lq + i * 4;
        size_t idx = ((size_t)b * L + l) * CDIM + c0 + cc;
        T[lq + i * 4][cc] = (bf2f(in[idx]) - mean) * rstd + bf2f(res[idx]);
    }
    __syncthreads();
    int ll = tid & 63;
    int cr = tid >> 6;
    #pragma unroll
    for (int i = 0; i < 16; ++i) {
        int c = cr + i * 4;
        outf[((size_t)b * CDIM + c0 + c) * L + l0 + ll] = T[ll][c];
    }
}

// ---------------------------------------------------------------------------
// MFMA 32x32 windowed cross attention, chunked double-buffered KV pipeline.
// 1D grid (704): p -> xcd = p&7, sub = p>>3; g = xcd*11 + sub%11; hh = sub/11;
// n = g%22, b = g/22 (8 heads of one (n,b) share an XCD's L2).
// qT: normalized q * (0.125*log2e*rstdK). kT/vT: RAW bf16 [B][L][CDIM].
// K-norm folded into Q (additive term cancels in softmax); V-norm applied in
// epilogue: out = rV*(PV/sum - muV). win out: (B,NH,NWIN,WINQ,HD) bf16.
// ---------------------------------------------------------------------------
__global__ __launch_bounds__(512, 2)
void attn_win_mfma32(const ushort_t* __restrict__ qT, const ushort_t* __restrict__ kT,
                     const ushort_t* __restrict__ vT,
                     const float* __restrict__ vmean, const float* __restrict__ vrstd,
                     ushort_t* __restrict__ win)
{
    __shared__ __align__(16) char KB[2][16384];        // K chunk: [128 kpos][64 d], swizzled
    __shared__ __align__(16) ushort_t VBv[2][64][132]; // V^T chunk: [64 d][128 kpos], padded
    __shared__ float VMS[64], VRS[64];

    int p = blockIdx.x;
    int xcd = p & 7;
    int sub = p >> 3;              // 0..87
    int g9 = xcd * 11 + (sub % 11);
    int hh = sub / 11;             // 0..7
    int n = g9 % 22, b = g9 / 22;

    int s = n * WSTRIDE;
    int es = 2 * s;
    bool tail = (n == NWIN - 1);
    int nch = tail ? 1 : 4;

    int tid = threadIdx.x;
    int lane = tid & 63;
    int w = tid >> 6;
    int l31 = lane & 31;
    int hf = lane >> 5;
    bool active = (!tail) || (w < 2);

    if (tid < 64) {
        int c = b * CDIM + hh * HD + tid;
        VMS[tid] = vmean[c];
        VRS[tid] = vrstd[c];
    }

    const ushort_t* kbase = kT + ((size_t)b * LEE + es) * CDIM + hh * HD;
    const ushort_t* vbase = vT + ((size_t)b * LEE + es) * CDIM + hh * HD;

    int vc8 = tid & 7;
    int vkp2 = tid >> 3;           // 0..63

    // chunk 0 staged up-front
    {
        #pragma unroll
        for (int i = 0; i < 2; ++i) {
            int gr = tid + i * 512;
            int kpos = gr >> 3;
            int c8 = (gr & 7) ^ (kpos & 7);
            gload16(kbase + (size_t)kpos * CDIM + c8 * 8, &KB[0][gr * 16]);
        }
        const ushort_t* src = vbase + (size_t)(2 * vkp2) * CDIM + vc8 * 8;
        u16x8 wa = *reinterpret_cast<const u16x8*>(src);
        u16x8 wb = *reinterpret_cast<const u16x8*>(src + CDIM);
        #pragma unroll
        for (int j = 0; j < 8; ++j) {
            int d = vc8 * 8 + j;
            uint32_t dw = (uint32_t)wa[j] | ((uint32_t)wb[j] << 16);
            *reinterpret_cast<uint32_t*>(&VBv[0][d][2 * vkp2]) = dw;
        }
    }

    // Q fragments (B-operand: col q = lane&31, k elems d = kd*16 + hf*8 + j)
    bf16x8 bq[4];
    if (active) {
        int qrow_g = s + w * 32 + l31;
        const ushort_t* qp = qT + ((size_t)b * LDD + qrow_g) * CDIM + hh * HD;
        #pragma unroll
        for (int kd = 0; kd < 4; ++kd)
            bq[kd] = *reinterpret_cast<const bf16x8*>(qp + kd * 16 + hf * 8);
    }

    f32x16 acc0, acc1;
    #pragma unroll
    for (int e = 0; e < 16; ++e) { acc0[e] = 0.f; acc1[e] = 0.f; }
    float m = -3e38f, ssum = 0.f;
    int swk = (lane & 7) << 4;

    for (int ch = 0; ch < nch; ++ch) {
        int buf = ch & 1;
        __syncthreads();                       // chunk ch staged; buf^1 free

        u16x8 wa, wb;
        bool pf = (ch + 1 < nch);
        if (pf) {
            // K prefetch: async direct-to-LDS
            #pragma unroll
            for (int i = 0; i < 2; ++i) {
                int gr = tid + i * 512;
                int kpos = gr >> 3;
                int c8 = (gr & 7) ^ (kpos & 7);
                gload16(kbase + (size_t)((ch + 1) * 128 + kpos) * CDIM + c8 * 8,
                        &KB[buf ^ 1][gr * 16]);
            }
            // V prefetch: issue loads now, write LDS after compute (T14)
            const ushort_t* src = vbase + (size_t)((ch + 1) * 128 + 2 * vkp2) * CDIM + vc8 * 8;
            wa = *reinterpret_cast<const u16x8*>(src);
            wb = *reinterpret_cast<const u16x8*>(src + CDIM);
        }

        if (active) {
            #pragma unroll 1
            for (int ccl = 0; ccl < 2; ++ccl) {
                // ---- S^T: A = K rows kpos, B = Q ----
                f32x16 st0, st1;
                #pragma unroll
                for (int e = 0; e < 16; ++e) { st0[e] = 0.f; st1[e] = 0.f; }
                const char* KA0 = &KB[buf][(ccl * 64 + l31) * 128];
                const char* KA1 = KA0 + 32 * 128;
                __builtin_amdgcn_s_setprio(1);
                #pragma unroll
                for (int kd = 0; kd < 4; ++kd) {
                    int co = (kd * 32 + hf * 16) ^ swk;
                    bf16x8 ka0 = *reinterpret_cast<const bf16x8*>(KA0 + co);
                    bf16x8 ka1 = *reinterpret_cast<const bf16x8*>(KA1 + co);
                    st0 = __builtin_amdgcn_mfma_f32_32x32x16_bf16(ka0, bq[kd], st0, 0, 0, 0);
                    st1 = __builtin_amdgcn_mfma_f32_32x32x16_bf16(ka1, bq[kd], st1, 0, 0, 0);
                }
                __builtin_amdgcn_s_setprio(0);
                // ---- online softmax (exp2 space), defer-max ----
                float pmax = st0[0];
                #pragma unroll
                for (int e = 1; e < 16; ++e) pmax = fmaxf(pmax, st0[e]);
                #pragma unroll
                for (int e = 0; e < 16; ++e) pmax = fmaxf(pmax, st1[e]);
                pmax = fmaxf(pmax, __shfl_xor(pmax, 32));
                if (!__all(pmax <= m + 11.5f)) {
                    float mnew = fmaxf(m, pmax);
                    float corr = exp2f(m - mnew);
                    m = mnew;
                    ssum *= corr;
                    #pragma unroll
                    for (int e = 0; e < 16; ++e) { acc0[e] *= corr; acc1[e] *= corr; }
                }
                uint32_t pk0[8], pk1[8];
                float ls = 0.f;
                #pragma unroll
                for (int pp = 0; pp < 8; ++pp) {
                    float a = exp2f(st0[2 * pp] - m), bb = exp2f(st0[2 * pp + 1] - m);
                    float c = exp2f(st1[2 * pp] - m), dd = exp2f(st1[2 * pp + 1] - m);
                    ls += (a + bb) + (c + dd);
                    pk0[pp] = pack2(a, bb);
                    pk1[pp] = pack2(c, dd);
                }
                ssum += ls;
                // ---- PV: O^T += V^T . P^T ----
                __builtin_amdgcn_s_setprio(1);
                #pragma unroll
                for (int kc = 0; kc < 4; ++kc) {
                    const int sub2 = kc & 1;
                    uint32_t pA0, pA1, pA2, pA3;
                    if ((kc >> 1) == 0) { pA0 = pk0[4*sub2]; pA1 = pk0[4*sub2+1]; pA2 = pk0[4*sub2+2]; pA3 = pk0[4*sub2+3]; }
                    else                { pA0 = pk1[4*sub2]; pA1 = pk1[4*sub2+1]; pA2 = pk1[4*sub2+2]; pA3 = pk1[4*sub2+3]; }
                    uint32_t s0 = hf ? pA0 : pA2;
                    uint32_t s1 = hf ? pA1 : pA3;
                    uint32_t r0 = (uint32_t)__shfl_xor((int)s0, 32);
                    uint32_t r1 = (uint32_t)__shfl_xor((int)s1, 32);
                    u32x4 bt;
                    bt[0] = hf ? r0 : pA0;
                    bt[1] = hf ? r1 : pA1;
                    bt[2] = hf ? pA2 : r0;
                    bt[3] = hf ? pA3 : r1;
                    bf16x8 pbf = __builtin_bit_cast(bf16x8, bt);
                    int ko = ccl * 64 + kc * 16 + hf * 8;
                    const uint32_t* vr0 = reinterpret_cast<const uint32_t*>(&VBv[buf][l31][ko]);
                    const uint32_t* vr1 = reinterpret_cast<const uint32_t*>(&VBv[buf][l31 + 32][ko]);
                    u32x2 alo = *reinterpret_cast<const u32x2*>(vr0);
                    u32x2 ahi = *reinterpret_cast<const u32x2*>(vr0 + 2);
                    u32x2 blo = *reinterpret_cast<const u32x2*>(vr1);
                    u32x2 bhi = *reinterpret_cast<const u32x2*>(vr1 + 2);
                    u32x4 va0u, va1u;
                    va0u[0] = alo[0]; va0u[1] = alo[1]; va0u[2] = ahi[0]; va0u[3] = ahi[1];
                    va1u[0] = blo[0]; va1u[1] = blo[1]; va1u[2] = bhi[0]; va1u[3] = bhi[1];
                    bf16x8 va0 = __builtin_bit_cast(bf16x8, va0u);
                    bf16x8 va1 = __builtin_bit_cast(bf16x8, va1u);
                    acc0 = __builtin_amdgcn_mfma_f32_32x32x16_bf16(va0, pbf, acc0, 0, 0, 0);
                    acc1 = __builtin_amdgcn_mfma_f32_32x32x16_bf16(va1, pbf, acc1, 0, 0, 0);
                }
                __builtin_amdgcn_s_setprio(0);
            }
        }

        if (pf) {
            // V write (loads have drained under compute)
            #pragma unroll
            for (int j = 0; j < 8; ++j) {
                int d = vc8 * 8 + j;
                uint32_t dw = (uint32_t)wa[j] | ((uint32_t)wb[j] << 16);
                *reinterpret_cast<uint32_t*>(&VBv[buf ^ 1][d][2 * vkp2]) = dw;
            }
        }
    }

    // ---- epilogue: out = rV * (acc/sum - muV); rows d = 8p + 4hf + e ----
    if (active) {
        float stot = ssum + __shfl_xor(ssum, 32);
        float rs = 1.f / stot;
        size_t wbase = (((size_t)(b * NHEAD + hh) * NWIN + n) * WINQ + (size_t)(w * 32 + l31)) * HD;
        #pragma unroll
        for (int p4 = 0; p4 < 4; ++p4) {
            int d0 = p4 * 8 + hf * 4;
            float o0[4], o1[4];
            #pragma unroll
            for (int e = 0; e < 4; ++e) {
                o0[e] = VRS[d0 + e] * (acc0[4 * p4 + e] * rs - VMS[d0 + e]);
                o1[e] = VRS[32 + d0 + e] * (acc1[4 * p4 + e] * rs - VMS[32 + d0 + e]);
            }
            u32x2 w0, w1v;
            w0[0] = pack2(o0[0], o0[1]); w0[1] = pack2(o0[2], o0[3]);
            w1v[0] = pack2(o1[0], o1[1]); w1v[1] = pack2(o1[2], o1[3]);
            *reinterpret_cast<u32x2*>(&win[wbase + p4 * 8 + hf * 4]) = w0;
            *reinterpret_cast<u32x2*>(&win[wbase + 32 + p4 * 8 + hf * 4]) = w1v;
        }
    }
}

// ---------------------------------------------------------------------------
// Overlap-add + count-normalize (bf16 win) -> bf16 [B][L][CDIM].
// grid (LDD/64, NHEAD, NB)
// ---------------------------------------------------------------------------
__global__ __launch_bounds__(256)
void attn_finalize(const ushort_t* __restrict__ win, ushort_t* __restrict__ outT)
{
    int l0 = blockIdx.x * 64;
    int hh = blockIdx.y, b = blockIdx.z;
    int tid = threadIdx.x;
    int d2 = tid & 31;            // d-pair index
    int lq = tid >> 5;            // 0..7
    #pragma unroll
    for (int i = 0; i < 8; ++i) {
        int ll = lq + i * 8;
        int l = l0 + ll;
        int n1 = min(NWIN - 1, l / WSTRIDE);
        int n0 = (l >= 64) ? ((l - 64) / WSTRIDE) : 0;
        float a0 = 0.f, a1 = 0.f;
        for (int nn = n0; nn <= n1; ++nn) {
            int qrow = l - nn * WSTRIDE;
            uint32_t v = *reinterpret_cast<const uint32_t*>(
                &win[(((size_t)(b * NHEAD + hh) * NWIN + nn) * WINQ + qrow) * HD + d2 * 2]);
            a0 += bf2f((ushort_t)(v & 0xffffu));
            a1 += bf2f((ushort_t)(v >> 16));
        }
        float inv = 1.f / (float)(n1 - n0 + 1);
        uint32_t o = pack2(a0 * inv, a1 * inv);
        *reinterpret_cast<uint32_t*>(
            &outT[((size_t)b * LDD + l) * CDIM + hh * HD + d2 * 2]) = o;
    }
}

// ---------------------------------------------------------------------------
extern "C" void kernel_launch(void* const* d_in, const int* in_sizes, int n_in,
                              void* d_out, int out_size, void* d_ws, size_t ws_size,
                              hipStream_t stream)
{
    const float* x_dec = (const float*)d_in[0];
    const float* x_enc = (const float*)d_in[1];
    const float* wq = (const float*)d_in[2];
    const float* bq = (const float*)d_in[3];
    const float* wk = (const float*)d_in[4];
    const float* bk = (const float*)d_in[5];
    const float* wv = (const float*)d_in[6];
    const float* bv = (const float*)d_in[7];
    const float* wo = (const float*)d_in[8];
    const float* bo = (const float*)d_in[9];
    const float* w1 = (const float*)d_in[10];
    const float* b1 = (const float*)d_in[11];
    const float* w2 = (const float*)d_in[12];
    const float* b2 = (const float*)d_in[13];
    float* out = (float*)d_out;

    // ---- workspace carve (bytes) ----
    char* base = (char*)d_ws;
    ushort_t* wqb = (ushort_t*)(base);
    ushort_t* wkb = (ushort_t*)(base + 524288);
    ushort_t* wvb = (ushort_t*)(base + 786432);
    ushort_t* wob = (ushort_t*)(base + 1048576);
    ushort_t* w1b = (ushort_t*)(base + 1572864);
    ushort_t* w2b = (ushort_t*)(base + 3670016);
    ushort_t* x_decT_b = (ushort_t*)(base + 5767168);    // 16.8 MB
    ushort_t* q_pre    = (ushort_t*)(base + 22544384);   // 16.8 MB -> xo_pre/xres
    ushort_t* k_pre    = (ushort_t*)(base + 39321600);   // 33.5 MB -> hT (with v)
    ushort_t* v_pre    = (ushort_t*)(base + 72876032);   // 33.5 MB
    ushort_t* x_encT_b = (ushort_t*)(base + 106430464);  // 16.8 MB -> attn_outT
    ushort_t* winb     = (ushort_t*)(base + 123207680);  // 23.1 MB bf16 -> y_pre
    float*    partQ    = (float*)(base + 169345024);     // 1 MB
    float*    partK    = (float*)(base + 170393600);     // 1 MB
    float*    partV    = (float*)(base + 171442176);     // 1 MB
    float*    km       = (float*)(base + 172490752);     // 8 KB each
    float*    krs      = km + 2048;
    float*    vm       = krs + 2048;
    float*    vrs      = vm + 2048;
    ushort_t* attn_outT = x_encT_b;
    ushort_t* xo_pre   = q_pre;
    ushort_t* hT       = k_pre;
    ushort_t* y_pre    = winb;

    dim3 blk(256);

    // 0. weights -> bf16
    Cvt6Args ca;
    ca.src[0] = wq; ca.src[1] = wk; ca.src[2] = wv;
    ca.src[3] = wo; ca.src[4] = w1; ca.src[5] = w2;
    ca.dst[0] = wqb; ca.dst[1] = wkb; ca.dst[2] = wvb;
    ca.dst[3] = wob; ca.dst[4] = w1b; ca.dst[5] = w2b;
    ca.n[0] = 262144; ca.n[1] = 131072; ca.n[2] = 131072;
    ca.n[3] = 262144; ca.n[4] = 1048576; ca.n[5] = 1048576;
    cvt6<<<dim3(1024, 6), blk, 0, stream>>>(ca);

    // 1. transpose inputs to [B][L][C] bf16
    tcvt<<<dim3(LDD / 64, CDIM / 64, NB), blk, 0, stream>>>(x_dec, x_decT_b, CDIM, LDD);
    tcvt<<<dim3(LEE / 64, CENC / 64, NB), blk, 0, stream>>>(x_enc, x_encT_b, CENC, LEE);

    const float QSCALE = 0.125f * 1.4426950408889634f;   // 1/sqrt(hd) * log2(e)

    // 2-4. q/k/v GEMMs (k/v stay RAW; stats captured for fused norms)
    mgemm2<0,1><<<dim3(CDIM / 128, LDD / 128, NB), blk, 0, stream>>>(x_decT_b, wqb, bq, q_pre, partQ, LDD, CDIM, CDIM);
    mgemm2<0,1><<<dim3(CDIM / 128, LEE / 128, NB), blk, 0, stream>>>(x_encT_b, wkb, bk, k_pre, partK, LEE, CDIM, CENC);
    mgemm2<0,1><<<dim3(CDIM / 128, LEE / 128, NB), blk, 0, stream>>>(x_encT_b, wvb, bv, v_pre, partV, LEE, CDIM, CENC);
    stats_finish<<<dim3(8), blk, 0, stream>>>(partK, partV, km, krs, vm, vrs);

    // 5. q normalized, folded with K's rstd (K-norm commutes into Q; mean
    //    term is a per-row additive constant -> cancels in softmax)
    cn_apply_v<0><<<dim3(LDD / 16, 1, NB), blk, 0, stream>>>(q_pre, partQ, nullptr, q_pre, krs, LDD, LDD / 128, QSCALE);

    // 6. windowed attention (chunked pipeline) + overlap-add
    attn_win_mfma32<<<dim3(NWIN * NHEAD * NB), dim3(512), 0, stream>>>(q_pre, k_pre, v_pre, vm, vrs, winb);
    attn_finalize<<<dim3(LDD / 64, NHEAD, NB), blk, 0, stream>>>(winb, attn_outT);

    // 7. xres = IN(attn_outT @ wo^T + bo) + x_decT
    mgemm2<0,1><<<dim3(CDIM / 128, LDD / 128, NB), blk, 0, stream>>>(attn_outT, wob, bo, xo_pre, partQ, LDD, CDIM, CDIM);
    cn_apply_v<1><<<dim3(LDD / 16, 1, NB), blk, 0, stream>>>(xo_pre, partQ, x_decT_b, xo_pre, nullptr, LDD, LDD / 128, 1.0f);

    // 8. h = gelu(xres @ w1^T + b1)
    mgemm2<1,0><<<dim3(HDIM / 128, LDD / 128, NB), blk, 0, stream>>>(xo_pre, w1b, b1, hT, nullptr, LDD, HDIM, CDIM);

    // 9. y = IN(h @ w2^T + b2) + xres -> f32 [B][C][L]
    mgemm2<0,1><<<dim3(CDIM / 128, LDD / 128, NB), blk, 0, stream>>>(hT, w2b, b2, y_pre, partQ, LDD, CDIM, HDIM);
    cn_apply_t<<<dim3(CDIM / 64, LDD / 64, NB), blk, 0, stream>>>(y_pre, partQ, xo_pre, out, LDD, LDD / 128);

    (void)in_sizes; (void)n_in; (void)out_size; (void)ws_size;
}